// Round 3
// baseline (1250.336 us; speedup 1.0000x reference)
//
#include <hip/hip_runtime.h>

// Block_58394375356873: HomoAttention transformer block, MI355X gfx950.
// I/O dtype: float32 (per reference). Internal GEMM compute: bf16 MFMA.
// M = B*N = 64*196 = 12544 = 98*128 row-tiles.

#define BATCH 64
#define SEQ   196
#define CH    768
#define NHEAD 12
#define HDIM  64
#define TOPK  16
#define HID   3072
#define MROWS 12544
#define MHALF 6272
#define SCALE_F 0.125f  // 64^-0.5

typedef __bf16 bf16x8 __attribute__((ext_vector_type(8)));
typedef float  f32x4  __attribute__((ext_vector_type(4)));

__device__ __forceinline__ unsigned short f2b(float f) {
    union { float f; unsigned int i; } c; c.f = f;
    unsigned int u = c.i;
    return (unsigned short)((u + 0x7fffu + ((u >> 16) & 1u)) >> 16); // RNE
}
__device__ __forceinline__ float b2f(unsigned short u) {
    union { unsigned int i; float f; } c; c.i = ((unsigned int)u) << 16; return c.f;
}
__device__ __forceinline__ float blo(unsigned int u) { return __uint_as_float(u << 16); }
__device__ __forceinline__ float bhi(unsigned int u) { return __uint_as_float(u & 0xffff0000u); }

// ---------------- f32 -> bf16 weight conversion (n % 4 == 0) ----------------
__global__ __launch_bounds__(256) void f2b_k(const float* __restrict__ src,
                                             unsigned short* __restrict__ dst, int n)
{
    int idx = (blockIdx.x * 256 + threadIdx.x) * 4;
    if (idx < n) {
        float4 v = *(const float4*)(src + idx);
        ushort4 o;
        o.x = f2b(v.x); o.y = f2b(v.y); o.z = f2b(v.z); o.w = f2b(v.w);
        *(ushort4*)(dst + idx) = o;
    }
}

// ---------------- LayerNorm: f32 in -> bf16 out, one block per row ----------------
__global__ __launch_bounds__(256) void ln_k(const float* __restrict__ x,
                                            const float* __restrict__ gw,
                                            const float* __restrict__ bw,
                                            unsigned short* __restrict__ out)
{
    const int row = blockIdx.x;
    const int tid = threadIdx.x;
    const float* xr = x + (size_t)row * CH;
    float v0 = xr[tid], v1 = xr[tid + 256], v2 = xr[tid + 512];
    float s  = v0 + v1 + v2;
    float sq = v0*v0 + v1*v1 + v2*v2;
#pragma unroll
    for (int off = 32; off > 0; off >>= 1) {
        s  += __shfl_down(s, off, 64);
        sq += __shfl_down(sq, off, 64);
    }
    __shared__ __align__(16) float red[8];
    if ((tid & 63) == 0) { red[(tid >> 6) * 2] = s; red[(tid >> 6) * 2 + 1] = sq; }
    __syncthreads();
    s  = red[0] + red[2] + red[4] + red[6];
    sq = red[1] + red[3] + red[5] + red[7];
    float mu  = s * (1.0f / CH);
    float var = sq * (1.0f / CH) - mu * mu;
    float rs  = rsqrtf(var + 1e-5f);
    unsigned short* orow = out + (size_t)row * CH;
    orow[tid]       = f2b((v0 - mu) * rs * gw[tid]       + bw[tid]);
    orow[tid + 256] = f2b((v1 - mu) * rs * gw[tid + 256] + bw[tid + 256]);
    orow[tid + 512] = f2b((v2 - mu) * rs * gw[tid + 512] + bw[tid + 512]);
}

// ---------------- NT GEMM: C[M,N] = A[M,K] @ W[N,K]^T (+bias)(+gelu)(+resid) ----
// A, W bf16; bias/resid f32; output bf16 (OUTF=false) or f32 (OUTF=true).
// 128x128 tile, 256 threads = 4 waves (2x2), each wave 4x4 of 16x16x32 MFMA.
template<bool BIAS, bool RES, bool GELU, bool OUTF>
__global__ __launch_bounds__(256, 2)
void gemm_bt(const unsigned short* __restrict__ A,
             const unsigned short* __restrict__ Bw,
             const float* __restrict__ bias,
             const float* __restrict__ resid,
             void* __restrict__ Cout,
             int M, int N, int K)
{
    __shared__ __align__(16) unsigned short As[128 * 32];
    __shared__ __align__(16) unsigned short Bs[128 * 32];
    const int tid  = threadIdx.x;
    const int w    = tid >> 6;
    const int lane = tid & 63;
    const int tileN = blockIdx.x * 128;
    const int tileM = blockIdx.y * 128;
    const int wm = (w >> 1) * 64, wn = (w & 1) * 64;
    const int q   = lane >> 4;
    const int l16 = lane & 15;

    f32x4 acc[4][4];
#pragma unroll
    for (int i = 0; i < 4; ++i)
#pragma unroll
        for (int j = 0; j < 4; ++j) acc[i][j] = (f32x4){0.f, 0.f, 0.f, 0.f};

    const int kIters = K >> 5;
    for (int kt = 0; kt < kIters; ++kt) {
        uint4 ra[2], rb[2];
#pragma unroll
        for (int c = 0; c < 2; ++c) {
            int idx = c * 256 + tid;                    // 16B chunk id, 0..511
            int row = idx >> 2, col8 = (idx & 3) * 8;   // row 0..127, col8 0/8/16/24
            ra[c] = *(const uint4*)(A  + (size_t)(tileM + row) * K + kt * 32 + col8);
            rb[c] = *(const uint4*)(Bw + (size_t)(tileN + row) * K + kt * 32 + col8);
        }
        __syncthreads();   // previous iteration's LDS reads done before overwrite
#pragma unroll
        for (int c = 0; c < 2; ++c) {
            int idx = c * 256 + tid;
            *(uint4*)&As[(size_t)idx * 8] = ra[c];
            *(uint4*)&Bs[(size_t)idx * 8] = rb[c];
        }
        __syncthreads();
        bf16x8 af[4], bfr[4];
#pragma unroll
        for (int i = 0; i < 4; ++i)
            af[i] = *(const bf16x8*)&As[(wm + i * 16 + l16) * 32 + q * 8];
#pragma unroll
        for (int j = 0; j < 4; ++j)
            bfr[j] = *(const bf16x8*)&Bs[(wn + j * 16 + l16) * 32 + q * 8];
#pragma unroll
        for (int i = 0; i < 4; ++i)
#pragma unroll
            for (int j = 0; j < 4; ++j)
                acc[i][j] = __builtin_amdgcn_mfma_f32_16x16x32_bf16(af[i], bfr[j], acc[i][j], 0, 0, 0);
    }

#pragma unroll
    for (int i = 0; i < 4; ++i) {
#pragma unroll
        for (int r = 0; r < 4; ++r) {
            int row = tileM + wm + i * 16 + q * 4 + r;  // C/D: col=lane&15, row=quad*4+reg
#pragma unroll
            for (int j = 0; j < 4; ++j) {
                int col = tileN + wn + j * 16 + l16;
                float v = acc[i][j][r];
                if (BIAS) v += bias[col];
                if (GELU) v = 0.5f * v * (1.0f + erff(v * 0.70710678118f));
                if (RES)  v += resid[(size_t)row * N + col];
                if (OUTF) ((float*)Cout)[(size_t)row * N + col] = v;
                else      ((unsigned short*)Cout)[(size_t)row * N + col] = f2b(v);
            }
        }
    }
}

// ---------------- Attention: scores + top-16 (sorted desc) + softmax ----------------
// One block per (b,h). Q,K tiles [196][64] bf16 in LDS (49 KB). Thread n owns row n.
__global__ __launch_bounds__(256) void attn_topk(const unsigned short* __restrict__ qk,
                                                 unsigned short* __restrict__ aout)
{
    const int bh = blockIdx.x;
    const int b = bh / NHEAD, h = bh % NHEAD;
    __shared__ __align__(16) unsigned int Qs[SEQ * 32];
    __shared__ __align__(16) unsigned int Ks[SEQ * 32];
    const unsigned int* qk32 = (const unsigned int*)qk;
    const int tid = threadIdx.x;
    const size_t rowbase = (((size_t)b * SEQ) * 1536 + h * 64) >> 1;  // uints
    for (int i = tid; i < SEQ * 32; i += 256) {
        int n = i >> 5, c = i & 31;
        size_t g = rowbase + (size_t)n * 768 + c;
        Qs[i] = qk32[g];
        Ks[i] = qk32[g + 384];  // k half at +768 bf16
    }
    __syncthreads();
    if (tid < SEQ) {
        float qv[64];
        const uint4* Q4 = (const uint4*)&Qs[tid * 32];
#pragma unroll
        for (int c4 = 0; c4 < 8; ++c4) {
            uint4 u = Q4[c4];
            qv[c4*8+0] = blo(u.x) * SCALE_F; qv[c4*8+1] = bhi(u.x) * SCALE_F;
            qv[c4*8+2] = blo(u.y) * SCALE_F; qv[c4*8+3] = bhi(u.y) * SCALE_F;
            qv[c4*8+4] = blo(u.z) * SCALE_F; qv[c4*8+5] = bhi(u.z) * SCALE_F;
            qv[c4*8+6] = blo(u.w) * SCALE_F; qv[c4*8+7] = bhi(u.w) * SCALE_F;
        }
        float t[TOPK];
#pragma unroll
        for (int j = 0; j < TOPK; ++j) t[j] = -1e30f;
        for (int m = 0; m < SEQ; ++m) {
            const uint4* K4 = (const uint4*)&Ks[m * 32];  // wave-uniform -> broadcast
            float p0 = 0.f, p1 = 0.f, p2 = 0.f, p3 = 0.f;
#pragma unroll
            for (int c4 = 0; c4 < 8; ++c4) {
                uint4 u = K4[c4];
                p0 += qv[c4*8+0] * blo(u.x); p0 += qv[c4*8+1] * bhi(u.x);
                p1 += qv[c4*8+2] * blo(u.y); p1 += qv[c4*8+3] * bhi(u.y);
                p2 += qv[c4*8+4] * blo(u.z); p2 += qv[c4*8+5] * bhi(u.z);
                p3 += qv[c4*8+6] * blo(u.w); p3 += qv[c4*8+7] * bhi(u.w);
            }
            float v = (p0 + p1) + (p2 + p3);
            // sorted (descending) top-16 insert, fully unrolled compare-swap
#pragma unroll
            for (int j = 0; j < TOPK; ++j) {
                float mx = fmaxf(t[j], v);
                v = fminf(t[j], v);
                t[j] = mx;
            }
        }
        float mx = t[0];
        float e[TOPK], sum = 0.f;
#pragma unroll
        for (int j = 0; j < TOPK; ++j) { e[j] = __expf(t[j] - mx); sum += e[j]; }
        float inv = 1.0f / sum;
        unsigned short* dst = aout + ((size_t)(b * SEQ + tid)) * (NHEAD * TOPK) + h * TOPK;
#pragma unroll
        for (int j = 0; j < TOPK; ++j) dst[j] = f2b(e[j] * inv);
    }
}

// ---------------- Launch ----------------
extern "C" void kernel_launch(void* const* d_in, const int* in_sizes, int n_in,
                              void* d_out, int out_size, void* d_ws, size_t ws_size,
                              hipStream_t stream)
{
    const float* x    = (const float*)d_in[0];
    const float* g1   = (const float*)d_in[1];
    const float* bb1  = (const float*)d_in[2];
    const float* qkw  = (const float*)d_in[3];
    const float* pw   = (const float*)d_in[4];
    const float* pb   = (const float*)d_in[5];
    const float* g2   = (const float*)d_in[6];
    const float* bb2  = (const float*)d_in[7];
    const float* f1w  = (const float*)d_in[8];
    const float* f1b  = (const float*)d_in[9];
    const float* f2w  = (const float*)d_in[10];
    const float* f2bp = (const float*)d_in[11];
    float* out = (float*)d_out;

    // workspace layout (bytes), peak ~74.7 MB:
    //   hbuf [0, 19.3M)    bf16 LN out (LN1, later LN2)
    //   qk   [.., +38.5M)  bf16; live GEMM2->attn; REUSED as gg per MLP half
    //   av   [.., +4.8M)   bf16 softmax weights
    //   wqk/wp/wf1/wf2 [.., +12.1M)  bf16 weights
    char* ws = (char*)d_ws;
    const size_t SZ_H  = (size_t)MROWS * CH  * 2;            // 19,267,584
    const size_t SZ_QK = (size_t)MROWS * 2 * CH * 2;         // 38,535,168
    const size_t SZ_A  = (size_t)MROWS * (NHEAD * TOPK) * 2; //  4,816,896
    unsigned short* hbuf = (unsigned short*)(ws);
    unsigned short* qk   = (unsigned short*)(ws + SZ_H);
    unsigned short* av   = (unsigned short*)(ws + SZ_H + SZ_QK);
    unsigned short* wqk  = (unsigned short*)(ws + SZ_H + SZ_QK + SZ_A);
    unsigned short* wp   = wqk + (size_t)2 * CH * CH;        // 1536*768
    unsigned short* wf1  = wp  + (size_t)CH * (NHEAD * TOPK);
    unsigned short* wf2  = wf1 + (size_t)HID * CH;
    unsigned short* gg   = qk;   // same region, disjoint lifetime (half-M)
    float* x1 = out;             // residual stream after attention lives in d_out

    // 0) convert weights f32 -> bf16
    f2b_k<<<(2*CH*CH/4 + 255)/256, 256, 0, stream>>>(qkw, wqk, 2*CH*CH);
    f2b_k<<<(CH*NHEAD*TOPK/4 + 255)/256, 256, 0, stream>>>(pw, wp, CH*NHEAD*TOPK);
    f2b_k<<<(HID*CH/4 + 255)/256, 256, 0, stream>>>(f1w, wf1, HID*CH);
    f2b_k<<<(HID*CH/4 + 255)/256, 256, 0, stream>>>(f2w, wf2, HID*CH);

    // 1) LN1: x -> h (bf16)
    ln_k<<<MROWS, 256, 0, stream>>>(x, g1, bb1, hbuf);
    // 2) qk = h @ qk_w^T   [12544 x 1536], K=768 -> bf16
    gemm_bt<false, false, false, false><<<dim3(2*CH/128, MROWS/128), 256, 0, stream>>>(
        hbuf, wqk, nullptr, nullptr, qk, MROWS, 2*CH, CH);
    // 3) attention scores -> top16 -> softmax -> a [12544 x 192] bf16
    attn_topk<<<BATCH * NHEAD, 256, 0, stream>>>(qk, av);
    // 4) x1 = x + a @ attn_proj_w^T + b   [12544 x 768], K=192 -> f32 (d_out)
    gemm_bt<true, true, false, true><<<dim3(CH/128, MROWS/128), 256, 0, stream>>>(
        av, wp, pb, x, x1, MROWS, CH, NHEAD*TOPK);
    // 5) LN2: x1 -> h2 (reuse hbuf)
    ln_k<<<MROWS, 256, 0, stream>>>(x1, g2, bb2, hbuf);
    // 6/7) MLP in two M-halves so the GELU intermediate fits qk's region
    for (int half = 0; half < 2; ++half) {
        const size_t ro = (size_t)half * MHALF;
        // g = gelu(h2 @ fc1_w^T + b)   [6272 x 3072], K=768 -> bf16
        gemm_bt<true, false, true, false><<<dim3(HID/128, MHALF/128), 256, 0, stream>>>(
            hbuf + ro * CH, wf1, f1b, nullptr, gg, MHALF, HID, CH);
        // out = x1 + g @ fc2_w^T + b   [6272 x 768], K=3072 -> f32 (1:1 rmw on d_out, safe)
        gemm_bt<true, true, false, true><<<dim3(CH/128, MHALF/128), 256, 0, stream>>>(
            gg, wf2, f2bp, x1 + ro * CH, out + ro * CH, MHALF, CH, HID);
    }
}

// Round 4
// 626.805 us; speedup vs baseline: 1.9948x; 1.9948x over previous
//
#include <hip/hip_runtime.h>

// Block_58394375356873: HomoAttention transformer block, MI355X gfx950.
// I/O dtype: float32 (per reference). Internal GEMM compute: bf16 MFMA.
// M = B*N = 64*196 = 12544 = 98*128 row-tiles.

#define BATCH 64
#define SEQ   196
#define CH    768
#define NHEAD 12
#define HDIM  64
#define TOPK  16
#define HID   3072
#define MROWS 12544
#define MHALF 6272
#define SCALE_F 0.125f  // 64^-0.5

typedef __bf16 bf16x8 __attribute__((ext_vector_type(8)));
typedef float  f32x4  __attribute__((ext_vector_type(4)));

__device__ __forceinline__ unsigned short f2b(float f) {
    union { float f; unsigned int i; } c; c.f = f;
    unsigned int u = c.i;
    return (unsigned short)((u + 0x7fffu + ((u >> 16) & 1u)) >> 16); // RNE
}
__device__ __forceinline__ float blo(unsigned int u) { return __uint_as_float(u << 16); }
__device__ __forceinline__ float bhi(unsigned int u) { return __uint_as_float(u & 0xffff0000u); }

// async global->LDS, 16B per lane. LDS base must be wave-uniform; HW adds lane*16.
__device__ __forceinline__ void async16(const unsigned short* g, unsigned short* l) {
    __builtin_amdgcn_global_load_lds(
        (const __attribute__((address_space(1))) unsigned int*)(g),
        (__attribute__((address_space(3))) unsigned int*)(l), 16, 0, 0);
}

// ---------------- f32 -> bf16 weight conversion (n % 4 == 0) ----------------
__global__ __launch_bounds__(256) void f2b_k(const float* __restrict__ src,
                                             unsigned short* __restrict__ dst, int n)
{
    int idx = (blockIdx.x * 256 + threadIdx.x) * 4;
    if (idx < n) {
        float4 v = *(const float4*)(src + idx);
        ushort4 o;
        o.x = f2b(v.x); o.y = f2b(v.y); o.z = f2b(v.z); o.w = f2b(v.w);
        *(ushort4*)(dst + idx) = o;
    }
}

// ---------------- LayerNorm: f32 in -> bf16 out, one block per row ----------------
__global__ __launch_bounds__(256) void ln_k(const float* __restrict__ x,
                                            const float* __restrict__ gw,
                                            const float* __restrict__ bw,
                                            unsigned short* __restrict__ out)
{
    const int row = blockIdx.x;
    const int tid = threadIdx.x;
    const float* xr = x + (size_t)row * CH;
    float v0 = xr[tid], v1 = xr[tid + 256], v2 = xr[tid + 512];
    float s  = v0 + v1 + v2;
    float sq = v0*v0 + v1*v1 + v2*v2;
#pragma unroll
    for (int off = 32; off > 0; off >>= 1) {
        s  += __shfl_down(s, off, 64);
        sq += __shfl_down(sq, off, 64);
    }
    __shared__ __align__(16) float red[8];
    if ((tid & 63) == 0) { red[(tid >> 6) * 2] = s; red[(tid >> 6) * 2 + 1] = sq; }
    __syncthreads();
    s  = red[0] + red[2] + red[4] + red[6];
    sq = red[1] + red[3] + red[5] + red[7];
    float mu  = s * (1.0f / CH);
    float var = sq * (1.0f / CH) - mu * mu;
    float rs  = rsqrtf(var + 1e-5f);
    unsigned short* orow = out + (size_t)row * CH;
    orow[tid]       = f2b((v0 - mu) * rs * gw[tid]       + bw[tid]);
    orow[tid + 256] = f2b((v1 - mu) * rs * gw[tid + 256] + bw[tid + 256]);
    orow[tid + 512] = f2b((v2 - mu) * rs * gw[tid + 512] + bw[tid + 512]);
}

// ---------------- NT GEMM: C[M,N] = A[M,K] @ W[N,K]^T (+bias)(+gelu)(+resid) ----
// A, W bf16; bias/resid f32; output bf16 (OUTF=false) or f32 (OUTF=true).
// 128x128 tile, 256 threads = 4 waves (2x2), each wave 4x4 of 16x16x32 MFMA.
// m97 structure: width-16 global_load_lds staging, 2 barriers per K-iter.
template<bool BIAS, bool RES, bool GELU, bool OUTF>
__global__ __launch_bounds__(256, 4)
void gemm_bt(const unsigned short* __restrict__ A,
             const unsigned short* __restrict__ Bw,
             const float* __restrict__ bias,
             const float* __restrict__ resid,
             void* __restrict__ Cout,
             int M, int N, int K)
{
    __shared__ __align__(16) unsigned short As[128 * 32];
    __shared__ __align__(16) unsigned short Bs[128 * 32];
    const int tid  = threadIdx.x;
    const int w    = tid >> 6;
    const int lane = tid & 63;
    const int tileN = blockIdx.x * 128;
    const int tileM = blockIdx.y * 128;
    const int wm = (w >> 1) * 64, wn = (w & 1) * 64;
    const int q   = lane >> 4;
    const int l16 = lane & 15;

    f32x4 acc[4][4];
#pragma unroll
    for (int i = 0; i < 4; ++i)
#pragma unroll
        for (int j = 0; j < 4; ++j) acc[i][j] = (f32x4){0.f, 0.f, 0.f, 0.f};

    // per-thread 16B chunk ids: idx0 = tid, idx1 = 256+tid
    // chunk idx -> row = idx>>2 (0..127), col8 = (idx&3)*8 (0/8/16/24)
    const int r0 = tid >> 2, c0 = (tid & 3) * 8;
    const int r1 = (256 + tid) >> 2, c1 = c0;   // (256+tid)&3 == tid&3

    const int kIters = K >> 5;
    for (int kt = 0; kt < kIters; ++kt) {
        __syncthreads();   // previous iteration's LDS reads complete before DMA overwrite
        {
            const unsigned short* ga0 = A  + (size_t)(tileM + r0) * K + kt * 32 + c0;
            const unsigned short* ga1 = A  + (size_t)(tileM + r1) * K + kt * 32 + c1;
            const unsigned short* gb0 = Bw + (size_t)(tileN + r0) * K + kt * 32 + c0;
            const unsigned short* gb1 = Bw + (size_t)(tileN + r1) * K + kt * 32 + c1;
            async16(ga0, As + (size_t)(w * 64) * 8);          // lanes deposit base+lane*16
            async16(ga1, As + (size_t)(256 + w * 64) * 8);
            async16(gb0, Bs + (size_t)(w * 64) * 8);
            async16(gb1, Bs + (size_t)(256 + w * 64) * 8);
        }
        __syncthreads();   // compiler drains vmcnt(0) before barrier -> DMA landed
        bf16x8 af[4], bfr[4];
#pragma unroll
        for (int i = 0; i < 4; ++i)
            af[i] = *(const bf16x8*)&As[(wm + i * 16 + l16) * 32 + q * 8];
#pragma unroll
        for (int j = 0; j < 4; ++j)
            bfr[j] = *(const bf16x8*)&Bs[(wn + j * 16 + l16) * 32 + q * 8];
#pragma unroll
        for (int i = 0; i < 4; ++i)
#pragma unroll
            for (int j = 0; j < 4; ++j)
                acc[i][j] = __builtin_amdgcn_mfma_f32_16x16x32_bf16(af[i], bfr[j], acc[i][j], 0, 0, 0);
    }

#pragma unroll
    for (int i = 0; i < 4; ++i) {
#pragma unroll
        for (int r = 0; r < 4; ++r) {
            int row = tileM + wm + i * 16 + q * 4 + r;  // C/D: col=lane&15, row=quad*4+reg
#pragma unroll
            for (int j = 0; j < 4; ++j) {
                int col = tileN + wn + j * 16 + l16;
                float v = acc[i][j][r];
                if (BIAS) v += bias[col];
                if (GELU) v = 0.5f * v * (1.0f + erff(v * 0.70710678118f));
                if (RES)  v += resid[(size_t)row * N + col];
                if (OUTF) ((float*)Cout)[(size_t)row * N + col] = v;
                else      ((unsigned short*)Cout)[(size_t)row * N + col] = f2b(v);
            }
        }
    }
}

// ---------------- Attention: scores + top-16 (sorted desc) + softmax ----------------
// One block per (b,h). Q,K tiles [196][64] bf16 in LDS (49 KB). Thread n owns row n.
__global__ __launch_bounds__(256) void attn_topk(const unsigned short* __restrict__ qk,
                                                 unsigned short* __restrict__ aout)
{
    const int bh = blockIdx.x;
    const int b = bh / NHEAD, h = bh % NHEAD;
    __shared__ __align__(16) unsigned int Qs[SEQ * 32];
    __shared__ __align__(16) unsigned int Ks[SEQ * 32];
    const unsigned int* qk32 = (const unsigned int*)qk;
    const int tid = threadIdx.x;
    const size_t rowbase = (((size_t)b * SEQ) * 1536 + h * 64) >> 1;  // uints
    for (int i = tid; i < SEQ * 32; i += 256) {
        int n = i >> 5, c = i & 31;
        size_t g = rowbase + (size_t)n * 768 + c;
        Qs[i] = qk32[g];
        Ks[i] = qk32[g + 384];  // k half at +768 bf16
    }
    __syncthreads();
    if (tid < SEQ) {
        float qv[64];
        const uint4* Q4 = (const uint4*)&Qs[tid * 32];
#pragma unroll
        for (int c4 = 0; c4 < 8; ++c4) {
            uint4 u = Q4[c4];
            qv[c4*8+0] = blo(u.x) * SCALE_F; qv[c4*8+1] = bhi(u.x) * SCALE_F;
            qv[c4*8+2] = blo(u.y) * SCALE_F; qv[c4*8+3] = bhi(u.y) * SCALE_F;
            qv[c4*8+4] = blo(u.z) * SCALE_F; qv[c4*8+5] = bhi(u.z) * SCALE_F;
            qv[c4*8+6] = blo(u.w) * SCALE_F; qv[c4*8+7] = bhi(u.w) * SCALE_F;
        }
        float t[TOPK];
#pragma unroll
        for (int j = 0; j < TOPK; ++j) t[j] = -1e30f;
        for (int m = 0; m < SEQ; ++m) {
            const uint4* K4 = (const uint4*)&Ks[m * 32];  // wave-uniform -> broadcast
            float p0 = 0.f, p1 = 0.f, p2 = 0.f, p3 = 0.f;
#pragma unroll
            for (int c4 = 0; c4 < 8; ++c4) {
                uint4 u = K4[c4];
                p0 += qv[c4*8+0] * blo(u.x); p0 += qv[c4*8+1] * bhi(u.x);
                p1 += qv[c4*8+2] * blo(u.y); p1 += qv[c4*8+3] * bhi(u.y);
                p2 += qv[c4*8+4] * blo(u.z); p2 += qv[c4*8+5] * bhi(u.z);
                p3 += qv[c4*8+6] * blo(u.w); p3 += qv[c4*8+7] * bhi(u.w);
            }
            float v = (p0 + p1) + (p2 + p3);
            // sorted (descending) top-16 insert, fully unrolled compare-swap
#pragma unroll
            for (int j = 0; j < TOPK; ++j) {
                float mx = fmaxf(t[j], v);
                v = fminf(t[j], v);
                t[j] = mx;
            }
        }
        float mx = t[0];
        float e[TOPK], sum = 0.f;
#pragma unroll
        for (int j = 0; j < TOPK; ++j) { e[j] = __expf(t[j] - mx); sum += e[j]; }
        float inv = 1.0f / sum;
        unsigned short* dst = aout + ((size_t)(b * SEQ + tid)) * (NHEAD * TOPK) + h * TOPK;
#pragma unroll
        for (int j = 0; j < TOPK; ++j) dst[j] = f2b(e[j] * inv);
    }
}

// ---------------- Launch ----------------
extern "C" void kernel_launch(void* const* d_in, const int* in_sizes, int n_in,
                              void* d_out, int out_size, void* d_ws, size_t ws_size,
                              hipStream_t stream)
{
    const float* x    = (const float*)d_in[0];
    const float* g1   = (const float*)d_in[1];
    const float* bb1  = (const float*)d_in[2];
    const float* qkw  = (const float*)d_in[3];
    const float* pw   = (const float*)d_in[4];
    const float* pb   = (const float*)d_in[5];
    const float* g2   = (const float*)d_in[6];
    const float* bb2  = (const float*)d_in[7];
    const float* f1w  = (const float*)d_in[8];
    const float* f1b  = (const float*)d_in[9];
    const float* f2w  = (const float*)d_in[10];
    const float* f2bp = (const float*)d_in[11];
    float* out = (float*)d_out;

    // workspace layout (bytes), peak ~74.7 MB:
    //   hbuf [0, 19.3M)    bf16 LN out (LN1, later LN2)
    //   qk   [.., +38.5M)  bf16; live GEMM2->attn; REUSED as gg per MLP half
    //   av   [.., +4.8M)   bf16 softmax weights
    //   wqk/wp/wf1/wf2 [.., +12.1M)  bf16 weights
    char* ws = (char*)d_ws;
    const size_t SZ_H  = (size_t)MROWS * CH  * 2;            // 19,267,584
    const size_t SZ_QK = (size_t)MROWS * 2 * CH * 2;         // 38,535,168
    const size_t SZ_A  = (size_t)MROWS * (NHEAD * TOPK) * 2; //  4,816,896
    unsigned short* hbuf = (unsigned short*)(ws);
    unsigned short* qk   = (unsigned short*)(ws + SZ_H);
    unsigned short* av   = (unsigned short*)(ws + SZ_H + SZ_QK);
    unsigned short* wqk  = (unsigned short*)(ws + SZ_H + SZ_QK + SZ_A);
    unsigned short* wp   = wqk + (size_t)2 * CH * CH;        // 1536*768
    unsigned short* wf1  = wp  + (size_t)CH * (NHEAD * TOPK);
    unsigned short* wf2  = wf1 + (size_t)HID * CH;
    unsigned short* gg   = qk;   // same region, disjoint lifetime (half-M)
    float* x1 = out;             // residual stream after attention lives in d_out

    // 0) convert weights f32 -> bf16
    f2b_k<<<(2*CH*CH/4 + 255)/256, 256, 0, stream>>>(qkw, wqk, 2*CH*CH);
    f2b_k<<<(CH*NHEAD*TOPK/4 + 255)/256, 256, 0, stream>>>(pw, wp, CH*NHEAD*TOPK);
    f2b_k<<<(HID*CH/4 + 255)/256, 256, 0, stream>>>(f1w, wf1, HID*CH);
    f2b_k<<<(HID*CH/4 + 255)/256, 256, 0, stream>>>(f2w, wf2, HID*CH);

    // 1) LN1: x -> h (bf16)
    ln_k<<<MROWS, 256, 0, stream>>>(x, g1, bb1, hbuf);
    // 2) qk = h @ qk_w^T   [12544 x 1536], K=768 -> bf16
    gemm_bt<false, false, false, false><<<dim3(2*CH/128, MROWS/128), 256, 0, stream>>>(
        hbuf, wqk, nullptr, nullptr, qk, MROWS, 2*CH, CH);
    // 3) attention scores -> top16 -> softmax -> a [12544 x 192] bf16
    attn_topk<<<BATCH * NHEAD, 256, 0, stream>>>(qk, av);
    // 4) x1 = x + a @ attn_proj_w^T + b   [12544 x 768], K=192 -> f32 (d_out)
    gemm_bt<true, true, false, true><<<dim3(CH/128, MROWS/128), 256, 0, stream>>>(
        av, wp, pb, x, x1, MROWS, CH, NHEAD*TOPK);
    // 5) LN2: x1 -> h2 (reuse hbuf)
    ln_k<<<MROWS, 256, 0, stream>>>(x1, g2, bb2, hbuf);
    // 6/7) MLP in two M-halves so the GELU intermediate fits qk's region
    for (int half = 0; half < 2; ++half) {
        const size_t ro = (size_t)half * MHALF;
        // g = gelu(h2 @ fc1_w^T + b)   [6272 x 3072], K=768 -> bf16
        gemm_bt<true, false, true, false><<<dim3(HID/128, MHALF/128), 256, 0, stream>>>(
            hbuf + ro * CH, wf1, f1b, nullptr, gg, MHALF, HID, CH);
        // out = x1 + g @ fc2_w^T + b   [6272 x 768], K=3072 -> f32 (1:1 rmw on d_out, safe)
        gemm_bt<true, true, false, true><<<dim3(CH/128, MHALF/128), 256, 0, stream>>>(
            gg, wf2, f2bp, x1 + ro * CH, out + ro * CH, MHALF, CH, HID);
    }
}

// Round 5
// 517.152 us; speedup vs baseline: 2.4177x; 1.2120x over previous
//
#include <hip/hip_runtime.h>

// Block_58394375356873: HomoAttention transformer block, MI355X gfx950.
// I/O dtype: float32 (per reference). Internal GEMM compute: bf16 MFMA.
// M = B*N = 64*196 = 12544 = 98*128 row-tiles.

#define BATCH 64
#define SEQ   196
#define CH    768
#define NHEAD 12
#define HDIM  64
#define TOPK  16
#define HID   3072
#define MROWS 12544
#define MHALF 6272
#define SCALE_F 0.125f  // 64^-0.5
#define NEGBIG -3e38f

typedef __bf16 bf16x8 __attribute__((ext_vector_type(8)));
typedef float  f32x4  __attribute__((ext_vector_type(4)));

__device__ __forceinline__ unsigned short f2b(float f) {
    union { float f; unsigned int i; } c; c.f = f;
    unsigned int u = c.i;
    return (unsigned short)((u + 0x7fffu + ((u >> 16) & 1u)) >> 16); // RNE
}

// async global->LDS, 16B per lane. LDS base must be wave-uniform; HW adds lane*16.
__device__ __forceinline__ void async16(const unsigned short* g, unsigned short* l) {
    __builtin_amdgcn_global_load_lds(
        (const __attribute__((address_space(1))) unsigned int*)(g),
        (__attribute__((address_space(3))) unsigned int*)(l), 16, 0, 0);
}

// ---------------- f32 -> bf16 weight conversion (n % 4 == 0) ----------------
__global__ __launch_bounds__(256) void f2b_k(const float* __restrict__ src,
                                             unsigned short* __restrict__ dst, int n)
{
    int idx = (blockIdx.x * 256 + threadIdx.x) * 4;
    if (idx < n) {
        float4 v = *(const float4*)(src + idx);
        ushort4 o;
        o.x = f2b(v.x); o.y = f2b(v.y); o.z = f2b(v.z); o.w = f2b(v.w);
        *(ushort4*)(dst + idx) = o;
    }
}

// ---------------- LayerNorm: f32 in -> bf16 out, one block per row ----------------
__global__ __launch_bounds__(256) void ln_k(const float* __restrict__ x,
                                            const float* __restrict__ gw,
                                            const float* __restrict__ bw,
                                            unsigned short* __restrict__ out)
{
    const int row = blockIdx.x;
    const int tid = threadIdx.x;
    const float* xr = x + (size_t)row * CH;
    float v0 = xr[tid], v1 = xr[tid + 256], v2 = xr[tid + 512];
    float s  = v0 + v1 + v2;
    float sq = v0*v0 + v1*v1 + v2*v2;
#pragma unroll
    for (int off = 32; off > 0; off >>= 1) {
        s  += __shfl_down(s, off, 64);
        sq += __shfl_down(sq, off, 64);
    }
    __shared__ __align__(16) float red[8];
    if ((tid & 63) == 0) { red[(tid >> 6) * 2] = s; red[(tid >> 6) * 2 + 1] = sq; }
    __syncthreads();
    s  = red[0] + red[2] + red[4] + red[6];
    sq = red[1] + red[3] + red[5] + red[7];
    float mu  = s * (1.0f / CH);
    float var = sq * (1.0f / CH) - mu * mu;
    float rs  = rsqrtf(var + 1e-5f);
    unsigned short* orow = out + (size_t)row * CH;
    orow[tid]       = f2b((v0 - mu) * rs * gw[tid]       + bw[tid]);
    orow[tid + 256] = f2b((v1 - mu) * rs * gw[tid + 256] + bw[tid + 256]);
    orow[tid + 512] = f2b((v2 - mu) * rs * gw[tid + 512] + bw[tid + 512]);
}

// ---------------- NT GEMM: C[M,N] = A[M,K] @ W[N,K]^T (+bias)(+gelu)(+resid) ----
// A, W bf16; bias/resid f32; output bf16 (OUTF=false) or f32 (OUTF=true).
// 128x128 tile, 256 threads = 4 waves (2x2), each wave 4x4 of 16x16x32 MFMA.
// m97 structure: width-16 global_load_lds staging, 2 barriers per K-iter.
template<bool BIAS, bool RES, bool GELU, bool OUTF>
__global__ __launch_bounds__(256, 4)
void gemm_bt(const unsigned short* __restrict__ A,
             const unsigned short* __restrict__ Bw,
             const float* __restrict__ bias,
             const float* __restrict__ resid,
             void* __restrict__ Cout,
             int M, int N, int K)
{
    __shared__ __align__(16) unsigned short As[128 * 32];
    __shared__ __align__(16) unsigned short Bs[128 * 32];
    const int tid  = threadIdx.x;
    const int w    = tid >> 6;
    const int lane = tid & 63;
    const int tileN = blockIdx.x * 128;
    const int tileM = blockIdx.y * 128;
    const int wm = (w >> 1) * 64, wn = (w & 1) * 64;
    const int q   = lane >> 4;
    const int l16 = lane & 15;

    f32x4 acc[4][4];
#pragma unroll
    for (int i = 0; i < 4; ++i)
#pragma unroll
        for (int j = 0; j < 4; ++j) acc[i][j] = (f32x4){0.f, 0.f, 0.f, 0.f};

    const int r0 = tid >> 2, c0 = (tid & 3) * 8;
    const int r1 = (256 + tid) >> 2, c1 = c0;

    const int kIters = K >> 5;
    for (int kt = 0; kt < kIters; ++kt) {
        __syncthreads();
        {
            const unsigned short* ga0 = A  + (size_t)(tileM + r0) * K + kt * 32 + c0;
            const unsigned short* ga1 = A  + (size_t)(tileM + r1) * K + kt * 32 + c1;
            const unsigned short* gb0 = Bw + (size_t)(tileN + r0) * K + kt * 32 + c0;
            const unsigned short* gb1 = Bw + (size_t)(tileN + r1) * K + kt * 32 + c1;
            async16(ga0, As + (size_t)(w * 64) * 8);
            async16(ga1, As + (size_t)(256 + w * 64) * 8);
            async16(gb0, Bs + (size_t)(w * 64) * 8);
            async16(gb1, Bs + (size_t)(256 + w * 64) * 8);
        }
        __syncthreads();
        bf16x8 af[4], bfr[4];
#pragma unroll
        for (int i = 0; i < 4; ++i)
            af[i] = *(const bf16x8*)&As[(wm + i * 16 + l16) * 32 + q * 8];
#pragma unroll
        for (int j = 0; j < 4; ++j)
            bfr[j] = *(const bf16x8*)&Bs[(wn + j * 16 + l16) * 32 + q * 8];
#pragma unroll
        for (int i = 0; i < 4; ++i)
#pragma unroll
            for (int j = 0; j < 4; ++j)
                acc[i][j] = __builtin_amdgcn_mfma_f32_16x16x32_bf16(af[i], bfr[j], acc[i][j], 0, 0, 0);
    }

#pragma unroll
    for (int i = 0; i < 4; ++i) {
#pragma unroll
        for (int r = 0; r < 4; ++r) {
            int row = tileM + wm + i * 16 + q * 4 + r;
#pragma unroll
            for (int j = 0; j < 4; ++j) {
                int col = tileN + wn + j * 16 + l16;
                float v = acc[i][j][r];
                if (BIAS) v += bias[col];
                if (GELU) v = 0.5f * v * (1.0f + erff(v * 0.70710678118f));
                if (RES)  v += resid[(size_t)row * N + col];
                if (OUTF) ((float*)Cout)[(size_t)row * N + col] = v;
                else      ((unsigned short*)Cout)[(size_t)row * N + col] = f2b(v);
            }
        }
    }
}

// ---------------- Attention: MFMA scores + in-register top-16 + softmax ----------------
// One block per (b,h). S^T = K @ Q^T via mfma_f32_16x16x32_bf16 (A=K: D-row=m,
// B=Q: D-col=n). Lane l16 owns column n; its quad sees m = tm*16 + q*4 + r.
// Each lane keeps a sorted-desc top-16 over its ~52 m-values, then 2 bitonic
// merges across quads (shfl_xor 16, 32) give the exact sorted top-16 per row.
// LDS: Q,K [208][64] bf16 with 16B-chunk XOR swizzle (chunk ^ (row&7)) so the
// MFMA frag reads are conflict-free.
__global__ __launch_bounds__(256) void attn_topk(const unsigned short* __restrict__ qk,
                                                 unsigned short* __restrict__ aout)
{
    const int bh = blockIdx.x;
    const int b = bh / NHEAD, h = bh % NHEAD;
    __shared__ __align__(16) unsigned short Qs[208 * 64];
    __shared__ __align__(16) unsigned short Ks[208 * 64];
    const int tid = threadIdx.x;

    // stage: 208 rows x 8 chunks of 16B, rows >=196 zero-filled
    for (int i = tid; i < 208 * 8; i += 256) {
        int row = i >> 3, c = i & 7;
        uint4 vq = make_uint4(0, 0, 0, 0), vk = vq;
        if (row < SEQ) {
            const uint4* gp = (const uint4*)(qk + ((size_t)(b * SEQ + row) * 1536 + h * 64));
            vq = gp[c];        // q half
            vk = gp[c + 96];   // k half: +768 shorts = +96 uint4
        }
        int slot = c ^ (row & 7);
        *(uint4*)&Qs[row * 64 + slot * 8] = vq;
        *(uint4*)&Ks[row * 64 + slot * 8] = vk;
    }
    __syncthreads();

    const int w = tid >> 6, lane = tid & 63;
    const int q = lane >> 4, l16 = lane & 15;

    for (int tn = w; tn < 13; tn += 4) {
        const int nrow = tn * 16 + l16;
        const int nsw = nrow & 7;
        bf16x8 bq0 = *(const bf16x8*)&Qs[nrow * 64 + ((0 ^ nsw) + (q ^ nsw) * 0) * 8 + ((q ^ nsw) * 8)];
        // (rewritten clearly below; chunk = kt*4+q, slot = chunk ^ (row&7))
        bq0 = *(const bf16x8*)&Qs[nrow * 64 + ((0 * 4 + q) ^ nsw) * 8];
        bf16x8 bq1 = *(const bf16x8*)&Qs[nrow * 64 + ((1 * 4 + q) ^ nsw) * 8];

        float t[TOPK];
#pragma unroll
        for (int j = 0; j < TOPK; ++j) t[j] = NEGBIG;

        // m-tiles 0..11: all 4 frag values valid
        for (int tm = 0; tm < 12; ++tm) {
            const int mrow = tm * 16 + l16;
            const int msw = mrow & 7;
            bf16x8 ak0 = *(const bf16x8*)&Ks[mrow * 64 + ((0 * 4 + q) ^ msw) * 8];
            bf16x8 ak1 = *(const bf16x8*)&Ks[mrow * 64 + ((1 * 4 + q) ^ msw) * 8];
            f32x4 acc = (f32x4){0.f, 0.f, 0.f, 0.f};
            acc = __builtin_amdgcn_mfma_f32_16x16x32_bf16(ak0, bq0, acc, 0, 0, 0);
            acc = __builtin_amdgcn_mfma_f32_16x16x32_bf16(ak1, bq1, acc, 0, 0, 0);
#pragma unroll
            for (int r = 0; r < 4; ++r) {
                float v = acc[r];
#pragma unroll
                for (int j = 0; j < TOPK; ++j) {
                    float mx = fmaxf(t[j], v);
                    v = fminf(t[j], v);
                    t[j] = mx;
                }
            }
        }
        // m-tile 12: m = 192 + q*4 + r; valid only for q==0 (m in 192..195)
        {
            const int mrow = 12 * 16 + l16;
            const int msw = mrow & 7;
            bf16x8 ak0 = *(const bf16x8*)&Ks[mrow * 64 + ((0 * 4 + q) ^ msw) * 8];
            bf16x8 ak1 = *(const bf16x8*)&Ks[mrow * 64 + ((1 * 4 + q) ^ msw) * 8];
            f32x4 acc = (f32x4){0.f, 0.f, 0.f, 0.f};
            acc = __builtin_amdgcn_mfma_f32_16x16x32_bf16(ak0, bq0, acc, 0, 0, 0);
            acc = __builtin_amdgcn_mfma_f32_16x16x32_bf16(ak1, bq1, acc, 0, 0, 0);
#pragma unroll
            for (int r = 0; r < 4; ++r) {
                float v = (q == 0) ? acc[r] : NEGBIG;
#pragma unroll
                for (int j = 0; j < TOPK; ++j) {
                    float mx = fmaxf(t[j], v);
                    v = fminf(t[j], v);
                    t[j] = mx;
                }
            }
        }

        // merge the 4 quads' sorted lists: xor 16 then xor 32
#pragma unroll
        for (int stage = 0; stage < 2; ++stage) {
            const int xm = 16 << stage;
            float bl[TOPK], c[TOPK];
#pragma unroll
            for (int j = 0; j < TOPK; ++j) bl[j] = __shfl_xor(t[j], xm, 64);
            // half-cleaner: top-16 of union (bitonic result)
#pragma unroll
            for (int j = 0; j < TOPK; ++j) c[j] = fmaxf(t[j], bl[TOPK - 1 - j]);
            // bitonic sort desc of bitonic 16-seq
#pragma unroll
            for (int s = 8; s >= 1; s >>= 1) {
#pragma unroll
                for (int i = 0; i < TOPK; ++i) {
                    if ((i & s) == 0) {
                        float mx = fmaxf(c[i], c[i + s]);
                        c[i + s] = fminf(c[i], c[i + s]);
                        c[i] = mx;
                    }
                }
            }
#pragma unroll
            for (int j = 0; j < TOPK; ++j) t[j] = c[j];
        }

        // softmax over sorted top-16 (scale folded in) and store (q==0 lanes)
        if (q == 0 && nrow < SEQ) {
            float e[TOPK], sum = 0.f;
#pragma unroll
            for (int j = 0; j < TOPK; ++j) { e[j] = __expf((t[j] - t[0]) * SCALE_F); sum += e[j]; }
            float inv = 1.0f / sum;
            unsigned int pk[8];
#pragma unroll
            for (int jj = 0; jj < 8; ++jj)
                pk[jj] = (unsigned int)f2b(e[2 * jj] * inv) |
                         ((unsigned int)f2b(e[2 * jj + 1] * inv) << 16);
            unsigned short* dst = aout + ((size_t)(b * SEQ + nrow)) * (NHEAD * TOPK) + h * TOPK;
            ((uint4*)dst)[0] = make_uint4(pk[0], pk[1], pk[2], pk[3]);
            ((uint4*)dst)[1] = make_uint4(pk[4], pk[5], pk[6], pk[7]);
        }
    }
}

// ---------------- Launch ----------------
extern "C" void kernel_launch(void* const* d_in, const int* in_sizes, int n_in,
                              void* d_out, int out_size, void* d_ws, size_t ws_size,
                              hipStream_t stream)
{
    const float* x    = (const float*)d_in[0];
    const float* g1   = (const float*)d_in[1];
    const float* bb1  = (const float*)d_in[2];
    const float* qkw  = (const float*)d_in[3];
    const float* pw   = (const float*)d_in[4];
    const float* pb   = (const float*)d_in[5];
    const float* g2   = (const float*)d_in[6];
    const float* bb2  = (const float*)d_in[7];
    const float* f1w  = (const float*)d_in[8];
    const float* f1b  = (const float*)d_in[9];
    const float* f2w  = (const float*)d_in[10];
    const float* f2bp = (const float*)d_in[11];
    float* out = (float*)d_out;

    char* ws = (char*)d_ws;
    const size_t SZ_H  = (size_t)MROWS * CH  * 2;            // 19,267,584
    const size_t SZ_QK = (size_t)MROWS * 2 * CH * 2;         // 38,535,168
    const size_t SZ_A  = (size_t)MROWS * (NHEAD * TOPK) * 2; //  4,816,896
    unsigned short* hbuf = (unsigned short*)(ws);
    unsigned short* qk   = (unsigned short*)(ws + SZ_H);
    unsigned short* av   = (unsigned short*)(ws + SZ_H + SZ_QK);
    unsigned short* wqk  = (unsigned short*)(ws + SZ_H + SZ_QK + SZ_A);
    unsigned short* wp   = wqk + (size_t)2 * CH * CH;
    unsigned short* wf1  = wp  + (size_t)CH * (NHEAD * TOPK);
    unsigned short* wf2  = wf1 + (size_t)HID * CH;
    unsigned short* gg   = qk;   // same region, disjoint lifetime (half-M)
    float* x1 = out;

    // 0) convert weights f32 -> bf16
    f2b_k<<<(2*CH*CH/4 + 255)/256, 256, 0, stream>>>(qkw, wqk, 2*CH*CH);
    f2b_k<<<(CH*NHEAD*TOPK/4 + 255)/256, 256, 0, stream>>>(pw, wp, CH*NHEAD*TOPK);
    f2b_k<<<(HID*CH/4 + 255)/256, 256, 0, stream>>>(f1w, wf1, HID*CH);
    f2b_k<<<(HID*CH/4 + 255)/256, 256, 0, stream>>>(f2w, wf2, HID*CH);

    // 1) LN1: x -> h (bf16)
    ln_k<<<MROWS, 256, 0, stream>>>(x, g1, bb1, hbuf);
    // 2) qk = h @ qk_w^T   [12544 x 1536], K=768 -> bf16
    gemm_bt<false, false, false, false><<<dim3(2*CH/128, MROWS/128), 256, 0, stream>>>(
        hbuf, wqk, nullptr, nullptr, qk, MROWS, 2*CH, CH);
    // 3) attention scores -> top16 -> softmax -> a [12544 x 192] bf16
    attn_topk<<<BATCH * NHEAD, 256, 0, stream>>>(qk, av);
    // 4) x1 = x + a @ attn_proj_w^T + b   [12544 x 768], K=192 -> f32 (d_out)
    gemm_bt<true, true, false, true><<<dim3(CH/128, MROWS/128), 256, 0, stream>>>(
        av, wp, pb, x, x1, MROWS, CH, NHEAD*TOPK);
    // 5) LN2: x1 -> h2 (reuse hbuf)
    ln_k<<<MROWS, 256, 0, stream>>>(x1, g2, bb2, hbuf);
    // 6/7) MLP in two M-halves so the GELU intermediate fits qk's region
    for (int half = 0; half < 2; ++half) {
        const size_t ro = (size_t)half * MHALF;
        gemm_bt<true, false, true, false><<<dim3(HID/128, MHALF/128), 256, 0, stream>>>(
            hbuf + ro * CH, wf1, f1b, nullptr, gg, MHALF, HID, CH);
        gemm_bt<true, true, false, true><<<dim3(CH/128, MHALF/128), 256, 0, stream>>>(
            gg, wf2, f2bp, x1 + ro * CH, out + ro * CH, MHALF, CH, HID);
    }
}

// Round 6
// 507.157 us; speedup vs baseline: 2.4654x; 1.0197x over previous
//
#include <hip/hip_runtime.h>

// Block_58394375356873: HomoAttention transformer block, MI355X gfx950.
// I/O dtype: float32 (per reference). Internal GEMM compute: bf16 MFMA.
// M = B*N = 64*196 = 12544 = 98*128 row-tiles.

#define BATCH 64
#define SEQ   196
#define CH    768
#define NHEAD 12
#define HDIM  64
#define TOPK  16
#define HID   3072
#define MROWS 12544
#define MHALF 6272
#define SCALE_F 0.125f  // 64^-0.5
#define NEGBIG -3e38f

typedef __bf16 bf16x8 __attribute__((ext_vector_type(8)));
typedef float  f32x4  __attribute__((ext_vector_type(4)));

__device__ __forceinline__ unsigned short f2b(float f) {
    union { float f; unsigned int i; } c; c.f = f;
    unsigned int u = c.i;
    return (unsigned short)((u + 0x7fffu + ((u >> 16) & 1u)) >> 16); // RNE
}

// async global->LDS, 16B per lane. LDS base must be wave-uniform; HW adds lane*16.
__device__ __forceinline__ void async16(const unsigned short* g, unsigned short* l) {
    __builtin_amdgcn_global_load_lds(
        (const __attribute__((address_space(1))) unsigned int*)(g),
        (__attribute__((address_space(3))) unsigned int*)(l), 16, 0, 0);
}

// ---------------- f32 -> bf16 weight conversion (n % 4 == 0) ----------------
__global__ __launch_bounds__(256) void f2b_k(const float* __restrict__ src,
                                             unsigned short* __restrict__ dst, int n)
{
    int idx = (blockIdx.x * 256 + threadIdx.x) * 4;
    if (idx < n) {
        float4 v = *(const float4*)(src + idx);
        ushort4 o;
        o.x = f2b(v.x); o.y = f2b(v.y); o.z = f2b(v.z); o.w = f2b(v.w);
        *(ushort4*)(dst + idx) = o;
    }
}

// ---------------- LayerNorm: f32 in -> bf16 out, one block per row ----------------
__global__ __launch_bounds__(256) void ln_k(const float* __restrict__ x,
                                            const float* __restrict__ gw,
                                            const float* __restrict__ bw,
                                            unsigned short* __restrict__ out)
{
    const int row = blockIdx.x;
    const int tid = threadIdx.x;
    const float* xr = x + (size_t)row * CH;
    float v0 = xr[tid], v1 = xr[tid + 256], v2 = xr[tid + 512];
    float s  = v0 + v1 + v2;
    float sq = v0*v0 + v1*v1 + v2*v2;
#pragma unroll
    for (int off = 32; off > 0; off >>= 1) {
        s  += __shfl_down(s, off, 64);
        sq += __shfl_down(sq, off, 64);
    }
    __shared__ __align__(16) float red[8];
    if ((tid & 63) == 0) { red[(tid >> 6) * 2] = s; red[(tid >> 6) * 2 + 1] = sq; }
    __syncthreads();
    s  = red[0] + red[2] + red[4] + red[6];
    sq = red[1] + red[3] + red[5] + red[7];
    float mu  = s * (1.0f / CH);
    float var = sq * (1.0f / CH) - mu * mu;
    float rs  = rsqrtf(var + 1e-5f);
    unsigned short* orow = out + (size_t)row * CH;
    orow[tid]       = f2b((v0 - mu) * rs * gw[tid]       + bw[tid]);
    orow[tid + 256] = f2b((v1 - mu) * rs * gw[tid + 256] + bw[tid + 256]);
    orow[tid + 512] = f2b((v2 - mu) * rs * gw[tid + 512] + bw[tid + 512]);
}

// ---------------- NT GEMM: C[M,N] = A[M,K] @ W[N,K]^T (+bias)(+gelu)(+resid) ----
// A, W bf16; bias/resid f32; output bf16 (OUTF=false) or f32 (OUTF=true).
// TM x 128 tile, 256 threads = 4 waves. TM=128: waves 2x2, 4x4 frags.
// TM=64: waves 1x4, 4x2 frags (for small grids: fc2, proj).
// Double-buffered width-16 global_load_lds: one barrier per K-iter; loads for
// kt+1 fly during compute on kt, hiding ~latency-minus-compute.
template<int TM, bool BIAS, bool RES, bool GELU, bool OUTF>
__global__ __launch_bounds__(256, 4)
void gemm_bt(const unsigned short* __restrict__ A,
             const unsigned short* __restrict__ Bw,
             const float* __restrict__ bias,
             const float* __restrict__ resid,
             void* __restrict__ Cout,
             int M, int N, int K)
{
    constexpr int WCOLS = (TM == 128) ? 2 : 4;
    constexpr int JF = 128 / (16 * WCOLS);          // frag cols per wave: 4 or 2
    __shared__ __align__(16) unsigned short As[2][TM * 32];
    __shared__ __align__(16) unsigned short Bs[2][128 * 32];
    const int tid  = threadIdx.x;
    const int w    = tid >> 6;
    const int lane = tid & 63;
    const int tileN = blockIdx.x * 128;
    const int tileM = blockIdx.y * TM;
    const int wm = (w / WCOLS) * 64;                // TM=64 -> always 0
    const int wn = (w % WCOLS) * (JF * 16);
    const int q   = lane >> 4;
    const int l16 = lane & 15;

    f32x4 acc[4][JF];
#pragma unroll
    for (int i = 0; i < 4; ++i)
#pragma unroll
        for (int j = 0; j < JF; ++j) acc[i][j] = (f32x4){0.f, 0.f, 0.f, 0.f};

    const int r0 = tid >> 2, c0 = (tid & 3) * 8;    // chunk tid: row r0, col8 c0

    const int kIters = K >> 5;

    auto stage = [&](int kt, int buf) {
        // B: 512 chunks (2/thread). chunk tid -> row r0; chunk 256+tid -> row r0+64.
        async16(Bw + (size_t)(tileN + r0) * K + kt * 32 + c0,
                &Bs[buf][(size_t)(w * 64) * 8]);
        async16(Bw + (size_t)(tileN + r0 + 64) * K + kt * 32 + c0,
                &Bs[buf][(size_t)(256 + w * 64) * 8]);
        // A: TM*4 chunks (1 or 2 per thread)
        async16(A + (size_t)(tileM + r0) * K + kt * 32 + c0,
                &As[buf][(size_t)(w * 64) * 8]);
        if constexpr (TM == 128) {
            async16(A + (size_t)(tileM + r0 + 64) * K + kt * 32 + c0,
                    &As[buf][(size_t)(256 + w * 64) * 8]);
        }
    };

    stage(0, 0);
    int cur = 0;
    for (int kt = 0; kt < kIters; ++kt) {
        __syncthreads();   // drains vmcnt: buf[cur] landed; prev iter's LDS reads done
        if (kt + 1 < kIters) stage(kt + 1, cur ^ 1);   // in flight during compute
        bf16x8 af[4], bfr[JF];
#pragma unroll
        for (int i = 0; i < 4; ++i)
            af[i] = *(const bf16x8*)&As[cur][(wm + i * 16 + l16) * 32 + q * 8];
#pragma unroll
        for (int j = 0; j < JF; ++j)
            bfr[j] = *(const bf16x8*)&Bs[cur][(wn + j * 16 + l16) * 32 + q * 8];
#pragma unroll
        for (int i = 0; i < 4; ++i)
#pragma unroll
            for (int j = 0; j < JF; ++j)
                acc[i][j] = __builtin_amdgcn_mfma_f32_16x16x32_bf16(af[i], bfr[j], acc[i][j], 0, 0, 0);
        cur ^= 1;
    }

#pragma unroll
    for (int i = 0; i < 4; ++i) {
#pragma unroll
        for (int r = 0; r < 4; ++r) {
            int row = tileM + wm + i * 16 + q * 4 + r;  // C/D: col=lane&15, row=quad*4+reg
#pragma unroll
            for (int j = 0; j < JF; ++j) {
                int col = tileN + wn + j * 16 + l16;
                float v = acc[i][j][r];
                if (BIAS) v += bias[col];
                if (GELU) v = 0.5f * v * (1.0f + erff(v * 0.70710678118f));
                if (RES)  v += resid[(size_t)row * N + col];
                if (OUTF) ((float*)Cout)[(size_t)row * N + col] = v;
                else      ((unsigned short*)Cout)[(size_t)row * N + col] = f2b(v);
            }
        }
    }
}

// ---------------- Attention: MFMA scores + in-register top-16 + softmax ----------------
// One block per (b,h). S^T = K @ Q^T via mfma_f32_16x16x32_bf16 (A=K: D-row=m,
// B=Q: D-col=n). Lane l16 owns column n; its quad sees m = tm*16 + q*4 + r.
// Each lane keeps a sorted-desc top-16 over its ~52 m-values, then 2 bitonic
// merges across quads (shfl_xor 16, 32) give the exact sorted top-16 per row.
// LDS: Q,K [208][64] bf16, 16B-chunk XOR swizzle (chunk ^ (row&7)): conflict-free.
__global__ __launch_bounds__(256) void attn_topk(const unsigned short* __restrict__ qk,
                                                 unsigned short* __restrict__ aout)
{
    const int bh = blockIdx.x;
    const int b = bh / NHEAD, h = bh % NHEAD;
    __shared__ __align__(16) unsigned short Qs[208 * 64];
    __shared__ __align__(16) unsigned short Ks[208 * 64];
    const int tid = threadIdx.x;

    for (int i = tid; i < 208 * 8; i += 256) {
        int row = i >> 3, c = i & 7;
        uint4 vq = make_uint4(0, 0, 0, 0), vk = vq;
        if (row < SEQ) {
            const uint4* gp = (const uint4*)(qk + ((size_t)(b * SEQ + row) * 1536 + h * 64));
            vq = gp[c];        // q half
            vk = gp[c + 96];   // k half: +768 shorts = +96 uint4
        }
        int slot = c ^ (row & 7);
        *(uint4*)&Qs[row * 64 + slot * 8] = vq;
        *(uint4*)&Ks[row * 64 + slot * 8] = vk;
    }
    __syncthreads();

    const int w = tid >> 6, lane = tid & 63;
    const int q = lane >> 4, l16 = lane & 15;

    for (int tn = w; tn < 13; tn += 4) {
        const int nrow = tn * 16 + l16;
        const int nsw = nrow & 7;
        bf16x8 bq0 = *(const bf16x8*)&Qs[nrow * 64 + ((0 * 4 + q) ^ nsw) * 8];
        bf16x8 bq1 = *(const bf16x8*)&Qs[nrow * 64 + ((1 * 4 + q) ^ nsw) * 8];

        float t[TOPK];
#pragma unroll
        for (int j = 0; j < TOPK; ++j) t[j] = NEGBIG;

        for (int tm = 0; tm < 12; ++tm) {
            const int mrow = tm * 16 + l16;
            const int msw = mrow & 7;
            bf16x8 ak0 = *(const bf16x8*)&Ks[mrow * 64 + ((0 * 4 + q) ^ msw) * 8];
            bf16x8 ak1 = *(const bf16x8*)&Ks[mrow * 64 + ((1 * 4 + q) ^ msw) * 8];
            f32x4 acc = (f32x4){0.f, 0.f, 0.f, 0.f};
            acc = __builtin_amdgcn_mfma_f32_16x16x32_bf16(ak0, bq0, acc, 0, 0, 0);
            acc = __builtin_amdgcn_mfma_f32_16x16x32_bf16(ak1, bq1, acc, 0, 0, 0);
#pragma unroll
            for (int r = 0; r < 4; ++r) {
                float v = acc[r];
#pragma unroll
                for (int j = 0; j < TOPK; ++j) {
                    float mx = fmaxf(t[j], v);
                    v = fminf(t[j], v);
                    t[j] = mx;
                }
            }
        }
        {   // m-tile 12: m = 192 + q*4 + r valid only for q==0
            const int mrow = 12 * 16 + l16;
            const int msw = mrow & 7;
            bf16x8 ak0 = *(const bf16x8*)&Ks[mrow * 64 + ((0 * 4 + q) ^ msw) * 8];
            bf16x8 ak1 = *(const bf16x8*)&Ks[mrow * 64 + ((1 * 4 + q) ^ msw) * 8];
            f32x4 acc = (f32x4){0.f, 0.f, 0.f, 0.f};
            acc = __builtin_amdgcn_mfma_f32_16x16x32_bf16(ak0, bq0, acc, 0, 0, 0);
            acc = __builtin_amdgcn_mfma_f32_16x16x32_bf16(ak1, bq1, acc, 0, 0, 0);
#pragma unroll
            for (int r = 0; r < 4; ++r) {
                float v = (q == 0) ? acc[r] : NEGBIG;
#pragma unroll
                for (int j = 0; j < TOPK; ++j) {
                    float mx = fmaxf(t[j], v);
                    v = fminf(t[j], v);
                    t[j] = mx;
                }
            }
        }

        // merge the 4 quads' sorted lists: xor 16 then xor 32
#pragma unroll
        for (int stage = 0; stage < 2; ++stage) {
            const int xm = 16 << stage;
            float bl[TOPK], c[TOPK];
#pragma unroll
            for (int j = 0; j < TOPK; ++j) bl[j] = __shfl_xor(t[j], xm, 64);
#pragma unroll
            for (int j = 0; j < TOPK; ++j) c[j] = fmaxf(t[j], bl[TOPK - 1 - j]);
#pragma unroll
            for (int s = 8; s >= 1; s >>= 1) {
#pragma unroll
                for (int i = 0; i < TOPK; ++i) {
                    if ((i & s) == 0) {
                        float mx = fmaxf(c[i], c[i + s]);
                        c[i + s] = fminf(c[i], c[i + s]);
                        c[i] = mx;
                    }
                }
            }
#pragma unroll
            for (int j = 0; j < TOPK; ++j) t[j] = c[j];
        }

        if (q == 0 && nrow < SEQ) {
            float e[TOPK], sum = 0.f;
#pragma unroll
            for (int j = 0; j < TOPK; ++j) { e[j] = __expf((t[j] - t[0]) * SCALE_F); sum += e[j]; }
            float inv = 1.0f / sum;
            unsigned int pk[8];
#pragma unroll
            for (int jj = 0; jj < 8; ++jj)
                pk[jj] = (unsigned int)f2b(e[2 * jj] * inv) |
                         ((unsigned int)f2b(e[2 * jj + 1] * inv) << 16);
            unsigned short* dst = aout + ((size_t)(b * SEQ + nrow)) * (NHEAD * TOPK) + h * TOPK;
            ((uint4*)dst)[0] = make_uint4(pk[0], pk[1], pk[2], pk[3]);
            ((uint4*)dst)[1] = make_uint4(pk[4], pk[5], pk[6], pk[7]);
        }
    }
}

// ---------------- Launch ----------------
extern "C" void kernel_launch(void* const* d_in, const int* in_sizes, int n_in,
                              void* d_out, int out_size, void* d_ws, size_t ws_size,
                              hipStream_t stream)
{
    const float* x    = (const float*)d_in[0];
    const float* g1   = (const float*)d_in[1];
    const float* bb1  = (const float*)d_in[2];
    const float* qkw  = (const float*)d_in[3];
    const float* pw   = (const float*)d_in[4];
    const float* pb   = (const float*)d_in[5];
    const float* g2   = (const float*)d_in[6];
    const float* bb2  = (const float*)d_in[7];
    const float* f1w  = (const float*)d_in[8];
    const float* f1b  = (const float*)d_in[9];
    const float* f2w  = (const float*)d_in[10];
    const float* f2bp = (const float*)d_in[11];
    float* out = (float*)d_out;

    char* ws = (char*)d_ws;
    const size_t SZ_H  = (size_t)MROWS * CH  * 2;            // 19,267,584
    const size_t SZ_QK = (size_t)MROWS * 2 * CH * 2;         // 38,535,168
    const size_t SZ_A  = (size_t)MROWS * (NHEAD * TOPK) * 2; //  4,816,896
    unsigned short* hbuf = (unsigned short*)(ws);
    unsigned short* qk   = (unsigned short*)(ws + SZ_H);
    unsigned short* av   = (unsigned short*)(ws + SZ_H + SZ_QK);
    unsigned short* wqk  = (unsigned short*)(ws + SZ_H + SZ_QK + SZ_A);
    unsigned short* wp   = wqk + (size_t)2 * CH * CH;
    unsigned short* wf1  = wp  + (size_t)CH * (NHEAD * TOPK);
    unsigned short* wf2  = wf1 + (size_t)HID * CH;
    unsigned short* gg   = qk;   // same region, disjoint lifetime (half-M)
    float* x1 = out;

    // 0) convert weights f32 -> bf16
    f2b_k<<<(2*CH*CH/4 + 255)/256, 256, 0, stream>>>(qkw, wqk, 2*CH*CH);
    f2b_k<<<(CH*NHEAD*TOPK/4 + 255)/256, 256, 0, stream>>>(pw, wp, CH*NHEAD*TOPK);
    f2b_k<<<(HID*CH/4 + 255)/256, 256, 0, stream>>>(f1w, wf1, HID*CH);
    f2b_k<<<(HID*CH/4 + 255)/256, 256, 0, stream>>>(f2w, wf2, HID*CH);

    // 1) LN1: x -> h (bf16)
    ln_k<<<MROWS, 256, 0, stream>>>(x, g1, bb1, hbuf);
    // 2) qk = h @ qk_w^T   [12544 x 1536], K=768 -> bf16   (grid 12x98)
    gemm_bt<128, false, false, false, false><<<dim3(2*CH/128, MROWS/128), 256, 0, stream>>>(
        hbuf, wqk, nullptr, nullptr, qk, MROWS, 2*CH, CH);
    // 3) attention scores -> top16 -> softmax -> a [12544 x 192] bf16
    attn_topk<<<BATCH * NHEAD, 256, 0, stream>>>(qk, av);
    // 4) x1 = x + a @ attn_proj_w^T + b   [12544 x 768], K=192 -> f32  (TM=64: grid 6x196)
    gemm_bt<64, true, true, false, true><<<dim3(CH/128, MROWS/64), 256, 0, stream>>>(
        av, wp, pb, x, x1, MROWS, CH, NHEAD*TOPK);
    // 5) LN2: x1 -> h2 (reuse hbuf)
    ln_k<<<MROWS, 256, 0, stream>>>(x1, g2, bb2, hbuf);
    // 6/7) MLP in two M-halves so the GELU intermediate fits qk's region
    for (int half = 0; half < 2; ++half) {
        const size_t ro = (size_t)half * MHALF;
        // g = gelu(h2 @ fc1_w^T + b)   [6272 x 3072], K=768 -> bf16  (grid 24x49)
        gemm_bt<128, true, false, true, false><<<dim3(HID/128, MHALF/128), 256, 0, stream>>>(
            hbuf + ro * CH, wf1, f1b, nullptr, gg, MHALF, HID, CH);
        // out = x1 + g @ fc2_w^T + b   [6272 x 768], K=3072 -> f32  (TM=64: grid 6x98)
        gemm_bt<64, true, true, false, true><<<dim3(CH/128, MHALF/64), 256, 0, stream>>>(
            gg, wf2, f2bp, x1 + ro * CH, out + ro * CH, MHALF, CH, HID);
    }
}

// Round 7
// 476.500 us; speedup vs baseline: 2.6240x; 1.0643x over previous
//
#include <hip/hip_runtime.h>

// Block_58394375356873: HomoAttention transformer block, MI355X gfx950.
// I/O dtype: float32 (per reference). Internal GEMM compute: bf16 MFMA.
// M = B*N = 64*196 = 12544.

#define BATCH 64
#define SEQ   196
#define CH    768
#define NHEAD 12
#define HDIM  64
#define TOPK  16
#define HID   3072
#define MROWS 12544
#define MHALF 6272
#define SCALE_F 0.125f  // 64^-0.5
#define NEGBIG -3e38f

typedef __bf16 bf16x8 __attribute__((ext_vector_type(8)));
typedef float  f32x4  __attribute__((ext_vector_type(4)));

__device__ __forceinline__ unsigned short f2b(float f) {
    union { float f; unsigned int i; } c; c.f = f;
    unsigned int u = c.i;
    return (unsigned short)((u + 0x7fffu + ((u >> 16) & 1u)) >> 16); // RNE
}

// async global->LDS, 16B per lane. LDS base must be wave-uniform; HW adds lane*16.
__device__ __forceinline__ void async16(const unsigned short* g, unsigned short* l) {
    __builtin_amdgcn_global_load_lds(
        (const __attribute__((address_space(1))) unsigned int*)(g),
        (__attribute__((address_space(3))) unsigned int*)(l), 16, 0, 0);
}

// ---------------- all-weights f32 -> bf16, one dispatch ----------------
__global__ __launch_bounds__(256) void f2b4_k(const float* __restrict__ s0, unsigned short* __restrict__ d0, int n0,
                                              const float* __restrict__ s1, unsigned short* __restrict__ d1, int n1,
                                              const float* __restrict__ s2, unsigned short* __restrict__ d2, int n2,
                                              const float* __restrict__ s3, unsigned short* __restrict__ d3, int n3)
{
    int idx = (blockIdx.x * 256 + threadIdx.x) * 4;
    const float* s; unsigned short* d; int n;
    if (idx < n0) { s = s0; d = d0; n = n0; }
    else {
        idx -= n0;
        if (idx < n1) { s = s1; d = d1; n = n1; }
        else {
            idx -= n1;
            if (idx < n2) { s = s2; d = d2; n = n2; }
            else { idx -= n2; s = s3; d = d3; n = n3; }
        }
    }
    if (idx < n) {
        float4 v = *(const float4*)(s + idx);
        ushort4 o;
        o.x = f2b(v.x); o.y = f2b(v.y); o.z = f2b(v.z); o.w = f2b(v.w);
        *(ushort4*)(d + idx) = o;
    }
}

// ---------------- LayerNorm: f32 in -> bf16 out, one block per row ----------------
__global__ __launch_bounds__(256) void ln_k(const float* __restrict__ x,
                                            const float* __restrict__ gw,
                                            const float* __restrict__ bw,
                                            unsigned short* __restrict__ out)
{
    const int row = blockIdx.x;
    const int tid = threadIdx.x;
    const float* xr = x + (size_t)row * CH;
    float v0 = xr[tid], v1 = xr[tid + 256], v2 = xr[tid + 512];
    float s  = v0 + v1 + v2;
    float sq = v0*v0 + v1*v1 + v2*v2;
#pragma unroll
    for (int off = 32; off > 0; off >>= 1) {
        s  += __shfl_down(s, off, 64);
        sq += __shfl_down(sq, off, 64);
    }
    __shared__ __align__(16) float red[8];
    if ((tid & 63) == 0) { red[(tid >> 6) * 2] = s; red[(tid >> 6) * 2 + 1] = sq; }
    __syncthreads();
    s  = red[0] + red[2] + red[4] + red[6];
    sq = red[1] + red[3] + red[5] + red[7];
    float mu  = s * (1.0f / CH);
    float var = sq * (1.0f / CH) - mu * mu;
    float rs  = rsqrtf(var + 1e-5f);
    unsigned short* orow = out + (size_t)row * CH;
    orow[tid]       = f2b((v0 - mu) * rs * gw[tid]       + bw[tid]);
    orow[tid + 256] = f2b((v1 - mu) * rs * gw[tid + 256] + bw[tid + 256]);
    orow[tid + 512] = f2b((v2 - mu) * rs * gw[tid + 512] + bw[tid + 512]);
}

// ---------------- NT GEMM: C[M,N] = A[M,K] @ W[N,K]^T (+bias)(+gelu)(+resid) ----
// 64x128 tile, BK=64 (two 32-sub-tiles), 256 threads = 4 waves splitting N.
// Double-buffered width-16 global_load_lds; one barrier per BK-iter. The
// overlap window for the prefetch = one full compute phase (32 MFMA-equiv).
template<bool BIAS, bool RES, bool GELU, bool OUTF>
__global__ __launch_bounds__(256, 3)
void gemm_bt64(const unsigned short* __restrict__ A,
               const unsigned short* __restrict__ Bw,
               const float* __restrict__ bias,
               const float* __restrict__ resid,
               void* __restrict__ Cout,
               int M, int N, int K)
{
    __shared__ __align__(16) unsigned short As[2][2][64 * 32];   // [buf][khalf]
    __shared__ __align__(16) unsigned short Bs[2][2][128 * 32];
    const int tid  = threadIdx.x;
    const int w    = tid >> 6;
    const int lane = tid & 63;
    const int tileN = blockIdx.x * 128;
    const int tileM = blockIdx.y * 64;
    const int wn = w * 32;
    const int q   = lane >> 4;
    const int l16 = lane & 15;

    f32x4 acc[4][2];
#pragma unroll
    for (int i = 0; i < 4; ++i)
#pragma unroll
        for (int j = 0; j < 2; ++j) acc[i][j] = (f32x4){0.f, 0.f, 0.f, 0.f};

    const int r0 = tid >> 2, c0 = (tid & 3) * 8;    // chunk tid -> row, col8

    const int kIters = K >> 6;

    auto stage = [&](int kt, int buf) {
#pragma unroll
        for (int h = 0; h < 2; ++h) {
            const size_t koff = (size_t)kt * 64 + h * 32;
            // A: 64 rows x 4 chunks = 256 chunks, 1/thread
            async16(A + (size_t)(tileM + r0) * K + koff + c0,
                    &As[buf][h][(size_t)(w * 64) * 8]);
            // B: 128 rows x 4 chunks = 512 chunks, 2/thread
            async16(Bw + (size_t)(tileN + r0) * K + koff + c0,
                    &Bs[buf][h][(size_t)(w * 64) * 8]);
            async16(Bw + (size_t)(tileN + r0 + 64) * K + koff + c0,
                    &Bs[buf][h][(size_t)(256 + w * 64) * 8]);
        }
    };

    stage(0, 0);
    int cur = 0;
    for (int kt = 0; kt < kIters; ++kt) {
        __syncthreads();   // drains vmcnt: buf[cur] landed; prior LDS reads done
        if (kt + 1 < kIters) stage(kt + 1, cur ^ 1);   // flies through compute phase
#pragma unroll
        for (int h = 0; h < 2; ++h) {
            bf16x8 af[4], bfr[2];
#pragma unroll
            for (int i = 0; i < 4; ++i)
                af[i] = *(const bf16x8*)&As[cur][h][(i * 16 + l16) * 32 + q * 8];
#pragma unroll
            for (int j = 0; j < 2; ++j)
                bfr[j] = *(const bf16x8*)&Bs[cur][h][(wn + j * 16 + l16) * 32 + q * 8];
#pragma unroll
            for (int i = 0; i < 4; ++i)
#pragma unroll
                for (int j = 0; j < 2; ++j)
                    acc[i][j] = __builtin_amdgcn_mfma_f32_16x16x32_bf16(af[i], bfr[j], acc[i][j], 0, 0, 0);
        }
        cur ^= 1;
    }

#pragma unroll
    for (int i = 0; i < 4; ++i) {
#pragma unroll
        for (int r = 0; r < 4; ++r) {
            int row = tileM + i * 16 + q * 4 + r;   // C/D: col=lane&15, row=quad*4+reg
#pragma unroll
            for (int j = 0; j < 2; ++j) {
                int col = tileN + wn + j * 16 + l16;
                float v = acc[i][j][r];
                if (BIAS) v += bias[col];
                if (GELU) v = 0.5f * v * (1.0f + erff(v * 0.70710678118f));
                if (RES)  v += resid[(size_t)row * N + col];
                if (OUTF) ((float*)Cout)[(size_t)row * N + col] = v;
                else      ((unsigned short*)Cout)[(size_t)row * N + col] = f2b(v);
            }
        }
    }
}

// ---------------- Attention: MFMA scores + in-register top-16 + softmax ----------------
// One block per (b,h). S^T = K @ Q^T via mfma_f32_16x16x32_bf16 (A=K: D-row=m,
// B=Q: D-col=n). Lane l16 owns column n; quad q sees m = tm*16 + q*4 + r.
// Per-lane sorted top-16, then 2 cross-quad bitonic merges (shfl_xor 16, 32).
// LDS: Q,K [208][64] bf16, 16B-chunk XOR swizzle (chunk ^ (row&7)): conflict-free.
__global__ __launch_bounds__(256) void attn_topk(const unsigned short* __restrict__ qk,
                                                 unsigned short* __restrict__ aout)
{
    const int bh = blockIdx.x;
    const int b = bh / NHEAD, h = bh % NHEAD;
    __shared__ __align__(16) unsigned short Qs[208 * 64];
    __shared__ __align__(16) unsigned short Ks[208 * 64];
    const int tid = threadIdx.x;

    for (int i = tid; i < 208 * 8; i += 256) {
        int row = i >> 3, c = i & 7;
        uint4 vq = make_uint4(0, 0, 0, 0), vk = vq;
        if (row < SEQ) {
            const uint4* gp = (const uint4*)(qk + ((size_t)(b * SEQ + row) * 1536 + h * 64));
            vq = gp[c];        // q half
            vk = gp[c + 96];   // k half: +768 shorts = +96 uint4
        }
        int slot = c ^ (row & 7);
        *(uint4*)&Qs[row * 64 + slot * 8] = vq;
        *(uint4*)&Ks[row * 64 + slot * 8] = vk;
    }
    __syncthreads();

    const int w = tid >> 6, lane = tid & 63;
    const int q = lane >> 4, l16 = lane & 15;

    for (int tn = w; tn < 13; tn += 4) {
        const int nrow = tn * 16 + l16;
        const int nsw = nrow & 7;
        bf16x8 bq0 = *(const bf16x8*)&Qs[nrow * 64 + ((0 * 4 + q) ^ nsw) * 8];
        bf16x8 bq1 = *(const bf16x8*)&Qs[nrow * 64 + ((1 * 4 + q) ^ nsw) * 8];

        float t[TOPK];
#pragma unroll
        for (int j = 0; j < TOPK; ++j) t[j] = NEGBIG;

        for (int tm = 0; tm < 12; ++tm) {
            const int mrow = tm * 16 + l16;
            const int msw = mrow & 7;
            bf16x8 ak0 = *(const bf16x8*)&Ks[mrow * 64 + ((0 * 4 + q) ^ msw) * 8];
            bf16x8 ak1 = *(const bf16x8*)&Ks[mrow * 64 + ((1 * 4 + q) ^ msw) * 8];
            f32x4 acc = (f32x4){0.f, 0.f, 0.f, 0.f};
            acc = __builtin_amdgcn_mfma_f32_16x16x32_bf16(ak0, bq0, acc, 0, 0, 0);
            acc = __builtin_amdgcn_mfma_f32_16x16x32_bf16(ak1, bq1, acc, 0, 0, 0);
#pragma unroll
            for (int r = 0; r < 4; ++r) {
                float v = acc[r];
#pragma unroll
                for (int j = 0; j < TOPK; ++j) {
                    float mx = fmaxf(t[j], v);
                    v = fminf(t[j], v);
                    t[j] = mx;
                }
            }
        }
        {   // m-tile 12: m = 192 + q*4 + r valid only for q==0
            const int mrow = 12 * 16 + l16;
            const int msw = mrow & 7;
            bf16x8 ak0 = *(const bf16x8*)&Ks[mrow * 64 + ((0 * 4 + q) ^ msw) * 8];
            bf16x8 ak1 = *(const bf16x8*)&Ks[mrow * 64 + ((1 * 4 + q) ^ msw) * 8];
            f32x4 acc = (f32x4){0.f, 0.f, 0.f, 0.f};
            acc = __builtin_amdgcn_mfma_f32_16x16x32_bf16(ak0, bq0, acc, 0, 0, 0);
            acc = __builtin_amdgcn_mfma_f32_16x16x32_bf16(ak1, bq1, acc, 0, 0, 0);
#pragma unroll
            for (int r = 0; r < 4; ++r) {
                float v = (q == 0) ? acc[r] : NEGBIG;
#pragma unroll
                for (int j = 0; j < TOPK; ++j) {
                    float mx = fmaxf(t[j], v);
                    v = fminf(t[j], v);
                    t[j] = mx;
                }
            }
        }

#pragma unroll
        for (int stage = 0; stage < 2; ++stage) {
            const int xm = 16 << stage;
            float bl[TOPK], c[TOPK];
#pragma unroll
            for (int j = 0; j < TOPK; ++j) bl[j] = __shfl_xor(t[j], xm, 64);
#pragma unroll
            for (int j = 0; j < TOPK; ++j) c[j] = fmaxf(t[j], bl[TOPK - 1 - j]);
#pragma unroll
            for (int s = 8; s >= 1; s >>= 1) {
#pragma unroll
                for (int i = 0; i < TOPK; ++i) {
                    if ((i & s) == 0) {
                        float mx = fmaxf(c[i], c[i + s]);
                        c[i + s] = fminf(c[i], c[i + s]);
                        c[i] = mx;
                    }
                }
            }
#pragma unroll
            for (int j = 0; j < TOPK; ++j) t[j] = c[j];
        }

        if (q == 0 && nrow < SEQ) {
            float e[TOPK], sum = 0.f;
#pragma unroll
            for (int j = 0; j < TOPK; ++j) { e[j] = __expf((t[j] - t[0]) * SCALE_F); sum += e[j]; }
            float inv = 1.0f / sum;
            unsigned int pk[8];
#pragma unroll
            for (int jj = 0; jj < 8; ++jj)
                pk[jj] = (unsigned int)f2b(e[2 * jj] * inv) |
                         ((unsigned int)f2b(e[2 * jj + 1] * inv) << 16);
            unsigned short* dst = aout + ((size_t)(b * SEQ + nrow)) * (NHEAD * TOPK) + h * TOPK;
            ((uint4*)dst)[0] = make_uint4(pk[0], pk[1], pk[2], pk[3]);
            ((uint4*)dst)[1] = make_uint4(pk[4], pk[5], pk[6], pk[7]);
        }
    }
}

// ---------------- Launch ----------------
extern "C" void kernel_launch(void* const* d_in, const int* in_sizes, int n_in,
                              void* d_out, int out_size, void* d_ws, size_t ws_size,
                              hipStream_t stream)
{
    const float* x    = (const float*)d_in[0];
    const float* g1   = (const float*)d_in[1];
    const float* bb1  = (const float*)d_in[2];
    const float* qkw  = (const float*)d_in[3];
    const float* pw   = (const float*)d_in[4];
    const float* pb   = (const float*)d_in[5];
    const float* g2   = (const float*)d_in[6];
    const float* bb2  = (const float*)d_in[7];
    const float* f1w  = (const float*)d_in[8];
    const float* f1b  = (const float*)d_in[9];
    const float* f2w  = (const float*)d_in[10];
    const float* f2bp = (const float*)d_in[11];
    float* out = (float*)d_out;

    // layout: hbuf | weights(wqk,wp,wf1,wf2) | av | qk/gg
    char* ws = (char*)d_ws;
    const size_t SZ_H   = (size_t)MROWS * CH * 2;              // 19,267,584
    const size_t N_WQK  = (size_t)2 * CH * CH;                 // 1,179,648 elems
    const size_t N_WP   = (size_t)CH * (NHEAD * TOPK);         //   147,456
    const size_t N_WF   = (size_t)HID * CH;                    // 2,359,296
    const size_t SZ_W   = (N_WQK + N_WP + 2 * N_WF) * 2;       // 12,091,392
    const size_t SZ_A   = (size_t)MROWS * (NHEAD * TOPK) * 2;  //  4,816,896
    const size_t SZ_QK  = (size_t)MROWS * 2 * CH * 2;          // 38,535,168
    const size_t SZ_GGF = (size_t)MROWS * HID * 2;             // 77,070,336

    unsigned short* hbuf = (unsigned short*)(ws);
    unsigned short* wqk  = (unsigned short*)(ws + SZ_H);
    unsigned short* wp   = wqk + N_WQK;
    unsigned short* wf1  = wp  + N_WP;
    unsigned short* wf2  = wf1 + N_WF;
    unsigned short* av   = (unsigned short*)(ws + SZ_H + SZ_W);
    unsigned short* qk   = (unsigned short*)(ws + SZ_H + SZ_W + SZ_A);
    unsigned short* gg   = qk;   // overlays qk (dead by MLP time)
    float* x1 = out;             // residual stream after attention lives in d_out

    const bool fullMLP = ws_size >= SZ_H + SZ_W + SZ_A + SZ_GGF;   // 113.25 MB

    // 0) all weights f32 -> bf16, one dispatch
    {
        int total4 = (int)((N_WQK + N_WP + 2 * N_WF) / 4);
        f2b4_k<<<(total4 + 255) / 256, 256, 0, stream>>>(
            qkw, wqk, (int)N_WQK, pw, wp, (int)N_WP,
            f1w, wf1, (int)N_WF, f2w, wf2, (int)N_WF);
    }

    // 1) LN1: x -> h (bf16)
    ln_k<<<MROWS, 256, 0, stream>>>(x, g1, bb1, hbuf);
    // 2) qk = h @ qk_w^T   [12544 x 1536], K=768   (grid 12x196)
    gemm_bt64<false, false, false, false><<<dim3(2*CH/128, MROWS/64), 256, 0, stream>>>(
        hbuf, wqk, nullptr, nullptr, qk, MROWS, 2*CH, CH);
    // 3) attention -> top16 softmax weights [12544 x 192] bf16
    attn_topk<<<BATCH * NHEAD, 256, 0, stream>>>(qk, av);
    // 4) x1 = x + a @ attn_proj_w^T + b   [12544 x 768], K=192   (grid 6x196)
    gemm_bt64<true, true, false, true><<<dim3(CH/128, MROWS/64), 256, 0, stream>>>(
        av, wp, pb, x, x1, MROWS, CH, NHEAD*TOPK);
    // 5) LN2: x1 -> h2 (reuse hbuf)
    ln_k<<<MROWS, 256, 0, stream>>>(x1, g2, bb2, hbuf);

    // 6/7) MLP: full-M if workspace allows (gg = 77 MB), else two M-halves
    if (fullMLP) {
        gemm_bt64<true, false, true, false><<<dim3(HID/128, MROWS/64), 256, 0, stream>>>(
            hbuf, wf1, f1b, nullptr, gg, MROWS, HID, CH);          // grid 24x196
        gemm_bt64<true, true, false, true><<<dim3(CH/128, MROWS/64), 256, 0, stream>>>(
            gg, wf2, f2bp, x1, out, MROWS, CH, HID);               // grid 6x196
    } else {
        for (int half = 0; half < 2; ++half) {
            const size_t ro = (size_t)half * MHALF;
            gemm_bt64<true, false, true, false><<<dim3(HID/128, MHALF/64), 256, 0, stream>>>(
                hbuf + ro * CH, wf1, f1b, nullptr, gg, MHALF, HID, CH);
            gemm_bt64<true, true, false, true><<<dim3(CH/128, MHALF/64), 256, 0, stream>>>(
                gg, wf2, f2bp, x1 + ro * CH, out + ro * CH, MHALF, CH, HID);
        }
    }
}

// Round 8
// 468.528 us; speedup vs baseline: 2.6687x; 1.0170x over previous
//
#include <hip/hip_runtime.h>

// Block_58394375356873: HomoAttention transformer block, MI355X gfx950.
// I/O dtype: float32 (per reference). Internal GEMM compute: bf16 MFMA.
// M = B*N = 64*196 = 12544.

#define BATCH 64
#define SEQ   196
#define CH    768
#define NHEAD 12
#define HDIM  64
#define TOPK  16
#define HID   3072
#define MROWS 12544
#define MHALF 6272
#define SCALE_F 0.125f  // 64^-0.5
#define NEGBIG -3e38f

typedef __bf16 bf16x8 __attribute__((ext_vector_type(8)));
typedef float  f32x4  __attribute__((ext_vector_type(4)));

__device__ __forceinline__ unsigned short f2b(float f) {
    union { float f; unsigned int i; } c; c.f = f;
    unsigned int u = c.i;
    return (unsigned short)((u + 0x7fffu + ((u >> 16) & 1u)) >> 16); // RNE
}

// async global->LDS, 16B per lane. LDS base must be wave-uniform; HW adds lane*16.
__device__ __forceinline__ void async16(const unsigned short* g, unsigned short* l) {
    __builtin_amdgcn_global_load_lds(
        (const __attribute__((address_space(1))) unsigned int*)(g),
        (__attribute__((address_space(3))) unsigned int*)(l), 16, 0, 0);
}

// ---------------- all-weights f32 -> bf16, one dispatch ----------------
__global__ __launch_bounds__(256) void f2b4_k(const float* __restrict__ s0, unsigned short* __restrict__ d0, int n0,
                                              const float* __restrict__ s1, unsigned short* __restrict__ d1, int n1,
                                              const float* __restrict__ s2, unsigned short* __restrict__ d2, int n2,
                                              const float* __restrict__ s3, unsigned short* __restrict__ d3, int n3)
{
    int idx = (blockIdx.x * 256 + threadIdx.x) * 4;
    const float* s; unsigned short* d; int n;
    if (idx < n0) { s = s0; d = d0; n = n0; }
    else {
        idx -= n0;
        if (idx < n1) { s = s1; d = d1; n = n1; }
        else {
            idx -= n1;
            if (idx < n2) { s = s2; d = d2; n = n2; }
            else { idx -= n2; s = s3; d = d3; n = n3; }
        }
    }
    if (idx < n) {
        float4 v = *(const float4*)(s + idx);
        ushort4 o;
        o.x = f2b(v.x); o.y = f2b(v.y); o.z = f2b(v.z); o.w = f2b(v.w);
        *(ushort4*)(d + idx) = o;
    }
}

// ---------------- LayerNorm: f32 in -> bf16 out, one block per row ----------------
__global__ __launch_bounds__(256) void ln_k(const float* __restrict__ x,
                                            const float* __restrict__ gw,
                                            const float* __restrict__ bw,
                                            unsigned short* __restrict__ out)
{
    const int row = blockIdx.x;
    const int tid = threadIdx.x;
    const float* xr = x + (size_t)row * CH;
    float v0 = xr[tid], v1 = xr[tid + 256], v2 = xr[tid + 512];
    float s  = v0 + v1 + v2;
    float sq = v0*v0 + v1*v1 + v2*v2;
#pragma unroll
    for (int off = 32; off > 0; off >>= 1) {
        s  += __shfl_down(s, off, 64);
        sq += __shfl_down(sq, off, 64);
    }
    __shared__ __align__(16) float red[8];
    if ((tid & 63) == 0) { red[(tid >> 6) * 2] = s; red[(tid >> 6) * 2 + 1] = sq; }
    __syncthreads();
    s  = red[0] + red[2] + red[4] + red[6];
    sq = red[1] + red[3] + red[5] + red[7];
    float mu  = s * (1.0f / CH);
    float var = sq * (1.0f / CH) - mu * mu;
    float rs  = rsqrtf(var + 1e-5f);
    unsigned short* orow = out + (size_t)row * CH;
    orow[tid]       = f2b((v0 - mu) * rs * gw[tid]       + bw[tid]);
    orow[tid + 256] = f2b((v1 - mu) * rs * gw[tid + 256] + bw[tid + 256]);
    orow[tid + 512] = f2b((v2 - mu) * rs * gw[tid + 512] + bw[tid + 512]);
}

// ---------------- NT GEMM: C[M,N] = A[M,K] @ W[N,K]^T (+bias)(+gelu)(+resid) ----
// TM x 128 tile, BK=32, 256 threads = 4 waves. TM=128: waves 2x2, 4x4 frags
// (128B LDS read per 16 MFMA per thread). TM=64: waves 1x4, 4x2 frags.
// Double-buffered width-16 global_load_lds, one barrier per K-iter.
// LDS XOR swizzle via SOURCE permutation (DMA deposit is lane-linear, so we
// permute which global chunk each lane fetches): slot c of row r holds global
// chunk c^(r&3); frag reads use chunk (q ^ (l16&3)). Banks: lanes 0-31 hit
// every bank exactly 4x per b128 -> zero conflicts (4-cycle minimum).
template<int TM, bool BIAS, bool RES, bool GELU, bool OUTF>
__global__ __launch_bounds__(256, 4)
void gemm_bt(const unsigned short* __restrict__ A,
             const unsigned short* __restrict__ Bw,
             const float* __restrict__ bias,
             const float* __restrict__ resid,
             void* __restrict__ Cout,
             int M, int N, int K)
{
    constexpr int WCOLS = (TM == 128) ? 2 : 4;
    constexpr int JF = 128 / (16 * WCOLS);          // frag cols per wave: 4 or 2
    __shared__ __align__(16) unsigned short As[2][TM * 32];
    __shared__ __align__(16) unsigned short Bs[2][128 * 32];
    const int tid  = threadIdx.x;
    const int w    = tid >> 6;
    const int lane = tid & 63;
    const int tileN = blockIdx.x * 128;
    const int tileM = blockIdx.y * TM;
    const int wm = (w / WCOLS) * 64;                // TM=64 -> 0
    const int wn = (w % WCOLS) * (JF * 16);
    const int q   = lane >> 4;
    const int l16 = lane & 15;
    const int csw = (q ^ (l16 & 3)) * 8;            // swizzled chunk offset for frag reads

    f32x4 acc[4][JF];
#pragma unroll
    for (int i = 0; i < 4; ++i)
#pragma unroll
        for (int j = 0; j < JF; ++j) acc[i][j] = (f32x4){0.f, 0.f, 0.f, 0.f};

    // staging: chunk idx -> row = idx>>2, slot = idx&3, global chunk = slot^(row&3)
    const int r0 = tid >> 2;
    const int g0 = ((tid & 3) ^ (r0 & 3)) * 8;      // chunks idx and idx+256 share row&3? no:
    const int r1 = r0 + 64;                         // idx+256 -> row+64; (row+64)&3 == row&3
    // so both chunks use the same source-chunk column g0.

    const int kIters = K >> 5;

    auto stage = [&](int kt, int buf) {
        const size_t koff = (size_t)kt * 32 + g0;
        async16(Bw + (size_t)(tileN + r0) * K + koff, &Bs[buf][(size_t)(w * 64) * 8]);
        async16(Bw + (size_t)(tileN + r1) * K + koff, &Bs[buf][(size_t)(256 + w * 64) * 8]);
        async16(A + (size_t)(tileM + r0) * K + koff, &As[buf][(size_t)(w * 64) * 8]);
        if constexpr (TM == 128) {
            async16(A + (size_t)(tileM + r1) * K + koff, &As[buf][(size_t)(256 + w * 64) * 8]);
        }
    };

    stage(0, 0);
    int cur = 0;
    for (int kt = 0; kt < kIters; ++kt) {
        __syncthreads();   // drains vmcnt: buf[cur] landed; prior LDS reads done
        if (kt + 1 < kIters) stage(kt + 1, cur ^ 1);   // flies through compute phase
        bf16x8 af[4], bfr[JF];
#pragma unroll
        for (int i = 0; i < 4; ++i)
            af[i] = *(const bf16x8*)&As[cur][(wm + i * 16 + l16) * 32 + csw];
#pragma unroll
        for (int j = 0; j < JF; ++j)
            bfr[j] = *(const bf16x8*)&Bs[cur][(wn + j * 16 + l16) * 32 + csw];
#pragma unroll
        for (int i = 0; i < 4; ++i)
#pragma unroll
            for (int j = 0; j < JF; ++j)
                acc[i][j] = __builtin_amdgcn_mfma_f32_16x16x32_bf16(af[i], bfr[j], acc[i][j], 0, 0, 0);
        cur ^= 1;
    }

#pragma unroll
    for (int i = 0; i < 4; ++i) {
#pragma unroll
        for (int r = 0; r < 4; ++r) {
            int row = tileM + wm + i * 16 + q * 4 + r;  // C/D: col=lane&15, row=quad*4+reg
#pragma unroll
            for (int j = 0; j < JF; ++j) {
                int col = tileN + wn + j * 16 + l16;
                float v = acc[i][j][r];
                if (BIAS) v += bias[col];
                if (GELU) v = 0.5f * v * (1.0f + erff(v * 0.70710678118f));
                if (RES)  v += resid[(size_t)row * N + col];
                if (OUTF) ((float*)Cout)[(size_t)row * N + col] = v;
                else      ((unsigned short*)Cout)[(size_t)row * N + col] = f2b(v);
            }
        }
    }
}

// ---------------- Attention: MFMA scores + in-register top-16 + softmax ----------------
// One block per (b,h). S^T = K @ Q^T via mfma_f32_16x16x32_bf16 (A=K: D-row=m,
// B=Q: D-col=n). Lane l16 owns column n; quad q sees m = tm*16 + q*4 + r.
// Per-lane sorted top-16, then 2 cross-quad bitonic merges (shfl_xor 16, 32).
// LDS: Q,K [208][64] bf16, 16B-chunk XOR swizzle (chunk ^ (row&7)): conflict-free.
__global__ __launch_bounds__(256) void attn_topk(const unsigned short* __restrict__ qk,
                                                 unsigned short* __restrict__ aout)
{
    const int bh = blockIdx.x;
    const int b = bh / NHEAD, h = bh % NHEAD;
    __shared__ __align__(16) unsigned short Qs[208 * 64];
    __shared__ __align__(16) unsigned short Ks[208 * 64];
    const int tid = threadIdx.x;

    for (int i = tid; i < 208 * 8; i += 256) {
        int row = i >> 3, c = i & 7;
        uint4 vq = make_uint4(0, 0, 0, 0), vk = vq;
        if (row < SEQ) {
            const uint4* gp = (const uint4*)(qk + ((size_t)(b * SEQ + row) * 1536 + h * 64));
            vq = gp[c];        // q half
            vk = gp[c + 96];   // k half: +768 shorts = +96 uint4
        }
        int slot = c ^ (row & 7);
        *(uint4*)&Qs[row * 64 + slot * 8] = vq;
        *(uint4*)&Ks[row * 64 + slot * 8] = vk;
    }
    __syncthreads();

    const int w = tid >> 6, lane = tid & 63;
    const int q = lane >> 4, l16 = lane & 15;

    for (int tn = w; tn < 13; tn += 4) {
        const int nrow = tn * 16 + l16;
        const int nsw = nrow & 7;
        bf16x8 bq0 = *(const bf16x8*)&Qs[nrow * 64 + ((0 * 4 + q) ^ nsw) * 8];
        bf16x8 bq1 = *(const bf16x8*)&Qs[nrow * 64 + ((1 * 4 + q) ^ nsw) * 8];

        float t[TOPK];
#pragma unroll
        for (int j = 0; j < TOPK; ++j) t[j] = NEGBIG;

        for (int tm = 0; tm < 12; ++tm) {
            const int mrow = tm * 16 + l16;
            const int msw = mrow & 7;
            bf16x8 ak0 = *(const bf16x8*)&Ks[mrow * 64 + ((0 * 4 + q) ^ msw) * 8];
            bf16x8 ak1 = *(const bf16x8*)&Ks[mrow * 64 + ((1 * 4 + q) ^ msw) * 8];
            f32x4 acc = (f32x4){0.f, 0.f, 0.f, 0.f};
            acc = __builtin_amdgcn_mfma_f32_16x16x32_bf16(ak0, bq0, acc, 0, 0, 0);
            acc = __builtin_amdgcn_mfma_f32_16x16x32_bf16(ak1, bq1, acc, 0, 0, 0);
#pragma unroll
            for (int r = 0; r < 4; ++r) {
                float v = acc[r];
#pragma unroll
                for (int j = 0; j < TOPK; ++j) {
                    float mx = fmaxf(t[j], v);
                    v = fminf(t[j], v);
                    t[j] = mx;
                }
            }
        }
        {   // m-tile 12: m = 192 + q*4 + r valid only for q==0
            const int mrow = 12 * 16 + l16;
            const int msw = mrow & 7;
            bf16x8 ak0 = *(const bf16x8*)&Ks[mrow * 64 + ((0 * 4 + q) ^ msw) * 8];
            bf16x8 ak1 = *(const bf16x8*)&Ks[mrow * 64 + ((1 * 4 + q) ^ msw) * 8];
            f32x4 acc = (f32x4){0.f, 0.f, 0.f, 0.f};
            acc = __builtin_amdgcn_mfma_f32_16x16x32_bf16(ak0, bq0, acc, 0, 0, 0);
            acc = __builtin_amdgcn_mfma_f32_16x16x32_bf16(ak1, bq1, acc, 0, 0, 0);
#pragma unroll
            for (int r = 0; r < 4; ++r) {
                float v = (q == 0) ? acc[r] : NEGBIG;
#pragma unroll
                for (int j = 0; j < TOPK; ++j) {
                    float mx = fmaxf(t[j], v);
                    v = fminf(t[j], v);
                    t[j] = mx;
                }
            }
        }

#pragma unroll
        for (int stage = 0; stage < 2; ++stage) {
            const int xm = 16 << stage;
            float bl[TOPK], c[TOPK];
#pragma unroll
            for (int j = 0; j < TOPK; ++j) bl[j] = __shfl_xor(t[j], xm, 64);
#pragma unroll
            for (int j = 0; j < TOPK; ++j) c[j] = fmaxf(t[j], bl[TOPK - 1 - j]);
#pragma unroll
            for (int s = 8; s >= 1; s >>= 1) {
#pragma unroll
                for (int i = 0; i < TOPK; ++i) {
                    if ((i & s) == 0) {
                        float mx = fmaxf(c[i], c[i + s]);
                        c[i + s] = fminf(c[i], c[i + s]);
                        c[i] = mx;
                    }
                }
            }
#pragma unroll
            for (int j = 0; j < TOPK; ++j) t[j] = c[j];
        }

        if (q == 0 && nrow < SEQ) {
            float e[TOPK], sum = 0.f;
#pragma unroll
            for (int j = 0; j < TOPK; ++j) { e[j] = __expf((t[j] - t[0]) * SCALE_F); sum += e[j]; }
            float inv = 1.0f / sum;
            unsigned int pk[8];
#pragma unroll
            for (int jj = 0; jj < 8; ++jj)
                pk[jj] = (unsigned int)f2b(e[2 * jj] * inv) |
                         ((unsigned int)f2b(e[2 * jj + 1] * inv) << 16);
            unsigned short* dst = aout + ((size_t)(b * SEQ + nrow)) * (NHEAD * TOPK) + h * TOPK;
            ((uint4*)dst)[0] = make_uint4(pk[0], pk[1], pk[2], pk[3]);
            ((uint4*)dst)[1] = make_uint4(pk[4], pk[5], pk[6], pk[7]);
        }
    }
}

// ---------------- Launch ----------------
extern "C" void kernel_launch(void* const* d_in, const int* in_sizes, int n_in,
                              void* d_out, int out_size, void* d_ws, size_t ws_size,
                              hipStream_t stream)
{
    const float* x    = (const float*)d_in[0];
    const float* g1   = (const float*)d_in[1];
    const float* bb1  = (const float*)d_in[2];
    const float* qkw  = (const float*)d_in[3];
    const float* pw   = (const float*)d_in[4];
    const float* pb   = (const float*)d_in[5];
    const float* g2   = (const float*)d_in[6];
    const float* bb2  = (const float*)d_in[7];
    const float* f1w  = (const float*)d_in[8];
    const float* f1b  = (const float*)d_in[9];
    const float* f2w  = (const float*)d_in[10];
    const float* f2bp = (const float*)d_in[11];
    float* out = (float*)d_out;

    // layout: hbuf | weights(wqk,wp,wf1,wf2) | av | qk/gg
    char* ws = (char*)d_ws;
    const size_t SZ_H   = (size_t)MROWS * CH * 2;              // 19,267,584
    const size_t N_WQK  = (size_t)2 * CH * CH;                 // 1,179,648 elems
    const size_t N_WP   = (size_t)CH * (NHEAD * TOPK);         //   147,456
    const size_t N_WF   = (size_t)HID * CH;                    // 2,359,296
    const size_t SZ_W   = (N_WQK + N_WP + 2 * N_WF) * 2;       // 12,091,392
    const size_t SZ_A   = (size_t)MROWS * (NHEAD * TOPK) * 2;  //  4,816,896
    const size_t SZ_GGF = (size_t)MROWS * HID * 2;             // 77,070,336

    unsigned short* hbuf = (unsigned short*)(ws);
    unsigned short* wqk  = (unsigned short*)(ws + SZ_H);
    unsigned short* wp   = wqk + N_WQK;
    unsigned short* wf1  = wp  + N_WP;
    unsigned short* wf2  = wf1 + N_WF;
    unsigned short* av   = (unsigned short*)(ws + SZ_H + SZ_W);
    unsigned short* qk   = (unsigned short*)(ws + SZ_H + SZ_W + SZ_A);
    unsigned short* gg   = qk;   // overlays qk (dead by MLP time)
    float* x1 = out;             // residual stream after attention lives in d_out

    const bool fullMLP = ws_size >= SZ_H + SZ_W + SZ_A + SZ_GGF;   // 113.25 MB

    // 0) all weights f32 -> bf16, one dispatch
    {
        int total4 = (int)((N_WQK + N_WP + 2 * N_WF) / 4);
        f2b4_k<<<(total4 + 255) / 256, 256, 0, stream>>>(
            qkw, wqk, (int)N_WQK, pw, wp, (int)N_WP,
            f1w, wf1, (int)N_WF, f2w, wf2, (int)N_WF);
    }

    // 1) LN1: x -> h (bf16)
    ln_k<<<MROWS, 256, 0, stream>>>(x, g1, bb1, hbuf);
    // 2) qk = h @ qk_w^T   [12544 x 1536], K=768   (TM=128: grid 12x98)
    gemm_bt<128, false, false, false, false><<<dim3(2*CH/128, MROWS/128), 256, 0, stream>>>(
        hbuf, wqk, nullptr, nullptr, qk, MROWS, 2*CH, CH);
    // 3) attention -> top16 softmax weights [12544 x 192] bf16
    attn_topk<<<BATCH * NHEAD, 256, 0, stream>>>(qk, av);
    // 4) x1 = x + a @ attn_proj_w^T + b   [12544 x 768], K=192   (TM=64: grid 6x196)
    gemm_bt<64, true, true, false, true><<<dim3(CH/128, MROWS/64), 256, 0, stream>>>(
        av, wp, pb, x, x1, MROWS, CH, NHEAD*TOPK);
    // 5) LN2: x1 -> h2 (reuse hbuf)
    ln_k<<<MROWS, 256, 0, stream>>>(x1, g2, bb2, hbuf);

    // 6/7) MLP: full-M if workspace allows (gg = 77 MB), else two M-halves
    if (fullMLP) {
        gemm_bt<128, true, false, true, false><<<dim3(HID/128, MROWS/128), 256, 0, stream>>>(
            hbuf, wf1, f1b, nullptr, gg, MROWS, HID, CH);          // grid 24x98
        gemm_bt<64, true, true, false, true><<<dim3(CH/128, MROWS/64), 256, 0, stream>>>(
            gg, wf2, f2bp, x1, out, MROWS, CH, HID);               // grid 6x196
    } else {
        for (int half = 0; half < 2; ++half) {
            const size_t ro = (size_t)half * MHALF;
            gemm_bt<128, true, false, true, false><<<dim3(HID/128, MHALF/128), 256, 0, stream>>>(
                hbuf + ro * CH, wf1, f1b, nullptr, gg, MHALF, HID, CH);
            gemm_bt<64, true, true, false, true><<<dim3(CH/128, MHALF/64), 256, 0, stream>>>(
                gg, wf2, f2bp, x1 + ro * CH, out + ro * CH, MHALF, CH, HID);
        }
    }
}

// Round 9
// 439.276 us; speedup vs baseline: 2.8464x; 1.0666x over previous
//
#include <hip/hip_runtime.h>

// Block_58394375356873: HomoAttention transformer block, MI355X gfx950.
// I/O dtype: float32 (per reference). Internal GEMM compute: bf16 MFMA.
// M = B*N = 64*196 = 12544.

#define BATCH 64
#define SEQ   196
#define CH    768
#define NHEAD 12
#define HDIM  64
#define TOPK  16
#define HID   3072
#define MROWS 12544
#define MHALF 6272
#define SCALE_F 0.125f  // 64^-0.5
#define NEGBIG -3e38f

typedef __bf16 bf16x8 __attribute__((ext_vector_type(8)));
typedef float  f32x4  __attribute__((ext_vector_type(4)));

__device__ __forceinline__ unsigned short f2b(float f) {
    union { float f; unsigned int i; } c; c.f = f;
    unsigned int u = c.i;
    return (unsigned short)((u + 0x7fffu + ((u >> 16) & 1u)) >> 16); // RNE
}

// async global->LDS, 16B per lane. LDS base must be wave-uniform; HW adds lane*16.
__device__ __forceinline__ void async16(const unsigned short* g, unsigned short* l) {
    __builtin_amdgcn_global_load_lds(
        (const __attribute__((address_space(1))) unsigned int*)(g),
        (__attribute__((address_space(3))) unsigned int*)(l), 16, 0, 0);
}

// ---------------- all-weights f32 -> bf16, one dispatch ----------------
__global__ __launch_bounds__(256) void f2b4_k(const float* __restrict__ s0, unsigned short* __restrict__ d0, int n0,
                                              const float* __restrict__ s1, unsigned short* __restrict__ d1, int n1,
                                              const float* __restrict__ s2, unsigned short* __restrict__ d2, int n2,
                                              const float* __restrict__ s3, unsigned short* __restrict__ d3, int n3)
{
    int idx = (blockIdx.x * 256 + threadIdx.x) * 4;
    const float* s; unsigned short* d; int n;
    if (idx < n0) { s = s0; d = d0; n = n0; }
    else {
        idx -= n0;
        if (idx < n1) { s = s1; d = d1; n = n1; }
        else {
            idx -= n1;
            if (idx < n2) { s = s2; d = d2; n = n2; }
            else { idx -= n2; s = s3; d = d3; n = n3; }
        }
    }
    if (idx < n) {
        float4 v = *(const float4*)(s + idx);
        ushort4 o;
        o.x = f2b(v.x); o.y = f2b(v.y); o.z = f2b(v.z); o.w = f2b(v.w);
        *(ushort4*)(d + idx) = o;
    }
}

// ---------------- LayerNorm: f32 in -> bf16 out, one block per row ----------------
__global__ __launch_bounds__(256) void ln_k(const float* __restrict__ x,
                                            const float* __restrict__ gw,
                                            const float* __restrict__ bw,
                                            unsigned short* __restrict__ out)
{
    const int row = blockIdx.x;
    const int tid = threadIdx.x;
    const float* xr = x + (size_t)row * CH;
    float v0 = xr[tid], v1 = xr[tid + 256], v2 = xr[tid + 512];
    float s  = v0 + v1 + v2;
    float sq = v0*v0 + v1*v1 + v2*v2;
#pragma unroll
    for (int off = 32; off > 0; off >>= 1) {
        s  += __shfl_down(s, off, 64);
        sq += __shfl_down(sq, off, 64);
    }
    __shared__ __align__(16) float red[8];
    if ((tid & 63) == 0) { red[(tid >> 6) * 2] = s; red[(tid >> 6) * 2 + 1] = sq; }
    __syncthreads();
    s  = red[0] + red[2] + red[4] + red[6];
    sq = red[1] + red[3] + red[5] + red[7];
    float mu  = s * (1.0f / CH);
    float var = sq * (1.0f / CH) - mu * mu;
    float rs  = rsqrtf(var + 1e-5f);
    unsigned short* orow = out + (size_t)row * CH;
    orow[tid]       = f2b((v0 - mu) * rs * gw[tid]       + bw[tid]);
    orow[tid + 256] = f2b((v1 - mu) * rs * gw[tid + 256] + bw[tid + 256]);
    orow[tid + 512] = f2b((v2 - mu) * rs * gw[tid + 512] + bw[tid + 512]);
}

// ---------------- NT GEMM: C[M,N] = A[M,K] @ W[N,K]^T (+bias)(+gelu)(+resid) ----
// TM x TN tile, BK=32, 256 threads = 4 waves. TM=128: waves 2x2. TM=64: 1x4.
// Double-buffered width-16 global_load_lds, one barrier per K-iter.
// Source-permuted LDS layout (slot c of row r holds global chunk c^(r&3)).
// XCD-locality swizzle: linear block ids are remapped so the gridN blocks
// sharing an A M-stripe have ids congruent mod 8 -> same XCD -> the stripe is
// HBM-fetched once per XCD and L2-served after (cuts both HBM traffic and
// average load latency under the dbuf window).
template<int TM, int TN, bool BIAS, bool RES, bool GELU, bool OUTF>
__global__ __launch_bounds__(256, 4)
void gemm_bt(const unsigned short* __restrict__ A,
             const unsigned short* __restrict__ Bw,
             const float* __restrict__ bias,
             const float* __restrict__ resid,
             void* __restrict__ Cout,
             int M, int N, int K)
{
    constexpr int WROWS = (TM == 128) ? 2 : 1;
    constexpr int WCOLS = 4 / WROWS;
    constexpr int JF = TN / (16 * WCOLS);           // frag cols per wave
    __shared__ __align__(16) unsigned short As[2][TM * 32];
    __shared__ __align__(16) unsigned short Bs[2][TN * 32];
    const int tid  = threadIdx.x;
    const int w    = tid >> 6;
    const int lane = tid & 63;

    // XCD-locality block remap (supergroups of 8 M-stripes x gridN)
    const int gridN = gridDim.x, gridM = gridDim.y;
    const int lid = blockIdx.y * gridN + blockIdx.x;
    const int SG = 8 * gridN;
    const int sg = lid / SG, r = lid % SG;
    const int remM = gridM - sg * 8;
    int mloc, nloc;
    if (remM >= 8) { mloc = sg * 8 + (r & 7); nloc = r >> 3; }
    else           { mloc = sg * 8 + r % remM; nloc = r / remM; }
    const int tileM = mloc * TM;
    const int tileN = nloc * TN;

    const int wm = (w / WCOLS) * 64;                // TM=64 -> 0
    const int wn = (w % WCOLS) * (JF * 16);
    const int q   = lane >> 4;
    const int l16 = lane & 15;
    const int csw = (q ^ (l16 & 3)) * 8;            // swizzled chunk offset for frag reads

    f32x4 acc[4][JF];
#pragma unroll
    for (int i = 0; i < 4; ++i)
#pragma unroll
        for (int j = 0; j < JF; ++j) acc[i][j] = (f32x4){0.f, 0.f, 0.f, 0.f};

    // staging: chunk idx -> row = idx>>2, slot = idx&3, global chunk = slot^(row&3)
    const int r0 = tid >> 2;
    const int g0 = ((tid & 3) ^ (r0 & 3)) * 8;      // (row+64k)&3 == row&3: same for all c

    const int kIters = K >> 5;

    auto stage = [&](int kt, int buf) {
        const size_t koff = (size_t)kt * 32 + g0;
#pragma unroll
        for (int c = 0; c < TN / 64; ++c)
            async16(Bw + (size_t)(tileN + r0 + c * 64) * K + koff,
                    &Bs[buf][(size_t)(c * 256 + w * 64) * 8]);
#pragma unroll
        for (int c = 0; c < TM / 64; ++c)
            async16(A + (size_t)(tileM + r0 + c * 64) * K + koff,
                    &As[buf][(size_t)(c * 256 + w * 64) * 8]);
    };

    stage(0, 0);
    int cur = 0;
    for (int kt = 0; kt < kIters; ++kt) {
        __syncthreads();   // drains vmcnt: buf[cur] landed; prior LDS reads done
        if (kt + 1 < kIters) stage(kt + 1, cur ^ 1);   // flies through compute phase
        bf16x8 af[4], bfr[JF];
#pragma unroll
        for (int i = 0; i < 4; ++i)
            af[i] = *(const bf16x8*)&As[cur][(wm + i * 16 + l16) * 32 + csw];
#pragma unroll
        for (int j = 0; j < JF; ++j)
            bfr[j] = *(const bf16x8*)&Bs[cur][(wn + j * 16 + l16) * 32 + csw];
#pragma unroll
        for (int i = 0; i < 4; ++i)
#pragma unroll
            for (int j = 0; j < JF; ++j)
                acc[i][j] = __builtin_amdgcn_mfma_f32_16x16x32_bf16(af[i], bfr[j], acc[i][j], 0, 0, 0);
        cur ^= 1;
    }

#pragma unroll
    for (int i = 0; i < 4; ++i) {
#pragma unroll
        for (int r2 = 0; r2 < 4; ++r2) {
            int row = tileM + wm + i * 16 + q * 4 + r2;  // C/D: col=lane&15, row=quad*4+reg
#pragma unroll
            for (int j = 0; j < JF; ++j) {
                int col = tileN + wn + j * 16 + l16;
                float v = acc[i][j][r2];
                if (BIAS) v += bias[col];
                if (GELU) v = 0.5f * v * (1.0f + erff(v * 0.70710678118f));
                if (RES)  v += resid[(size_t)row * N + col];
                if (OUTF) ((float*)Cout)[(size_t)row * N + col] = v;
                else      ((unsigned short*)Cout)[(size_t)row * N + col] = f2b(v);
            }
        }
    }
}

// ---------------- Attention: MFMA scores + in-register top-16 + softmax ----------------
// One block per (b,h). S^T = K @ Q^T via mfma_f32_16x16x32_bf16 (A=K: D-row=m,
// B=Q: D-col=n). Lane l16 owns column n; quad q sees m = tm*16 + q*4 + r.
// Per-lane sorted top-16, then 2 cross-quad bitonic merges (shfl_xor 16, 32).
// LDS: Q,K [208][64] bf16, 16B-chunk XOR swizzle (chunk ^ (row&7)): conflict-free.
__global__ __launch_bounds__(256) void attn_topk(const unsigned short* __restrict__ qk,
                                                 unsigned short* __restrict__ aout)
{
    const int bh = blockIdx.x;
    const int b = bh / NHEAD, h = bh % NHEAD;
    __shared__ __align__(16) unsigned short Qs[208 * 64];
    __shared__ __align__(16) unsigned short Ks[208 * 64];
    const int tid = threadIdx.x;

    for (int i = tid; i < 208 * 8; i += 256) {
        int row = i >> 3, c = i & 7;
        uint4 vq = make_uint4(0, 0, 0, 0), vk = vq;
        if (row < SEQ) {
            const uint4* gp = (const uint4*)(qk + ((size_t)(b * SEQ + row) * 1536 + h * 64));
            vq = gp[c];        // q half
            vk = gp[c + 96];   // k half: +768 shorts = +96 uint4
        }
        int slot = c ^ (row & 7);
        *(uint4*)&Qs[row * 64 + slot * 8] = vq;
        *(uint4*)&Ks[row * 64 + slot * 8] = vk;
    }
    __syncthreads();

    const int w = tid >> 6, lane = tid & 63;
    const int q = lane >> 4, l16 = lane & 15;

    for (int tn = w; tn < 13; tn += 4) {
        const int nrow = tn * 16 + l16;
        const int nsw = nrow & 7;
        bf16x8 bq0 = *(const bf16x8*)&Qs[nrow * 64 + ((0 * 4 + q) ^ nsw) * 8];
        bf16x8 bq1 = *(const bf16x8*)&Qs[nrow * 64 + ((1 * 4 + q) ^ nsw) * 8];

        float t[TOPK];
#pragma unroll
        for (int j = 0; j < TOPK; ++j) t[j] = NEGBIG;

        for (int tm = 0; tm < 12; ++tm) {
            const int mrow = tm * 16 + l16;
            const int msw = mrow & 7;
            bf16x8 ak0 = *(const bf16x8*)&Ks[mrow * 64 + ((0 * 4 + q) ^ msw) * 8];
            bf16x8 ak1 = *(const bf16x8*)&Ks[mrow * 64 + ((1 * 4 + q) ^ msw) * 8];
            f32x4 acc = (f32x4){0.f, 0.f, 0.f, 0.f};
            acc = __builtin_amdgcn_mfma_f32_16x16x32_bf16(ak0, bq0, acc, 0, 0, 0);
            acc = __builtin_amdgcn_mfma_f32_16x16x32_bf16(ak1, bq1, acc, 0, 0, 0);
#pragma unroll
            for (int r = 0; r < 4; ++r) {
                float v = acc[r];
#pragma unroll
                for (int j = 0; j < TOPK; ++j) {
                    float mx = fmaxf(t[j], v);
                    v = fminf(t[j], v);
                    t[j] = mx;
                }
            }
        }
        {   // m-tile 12: m = 192 + q*4 + r valid only for q==0
            const int mrow = 12 * 16 + l16;
            const int msw = mrow & 7;
            bf16x8 ak0 = *(const bf16x8*)&Ks[mrow * 64 + ((0 * 4 + q) ^ msw) * 8];
            bf16x8 ak1 = *(const bf16x8*)&Ks[mrow * 64 + ((1 * 4 + q) ^ msw) * 8];
            f32x4 acc = (f32x4){0.f, 0.f, 0.f, 0.f};
            acc = __builtin_amdgcn_mfma_f32_16x16x32_bf16(ak0, bq0, acc, 0, 0, 0);
            acc = __builtin_amdgcn_mfma_f32_16x16x32_bf16(ak1, bq1, acc, 0, 0, 0);
#pragma unroll
            for (int r = 0; r < 4; ++r) {
                float v = (q == 0) ? acc[r] : NEGBIG;
#pragma unroll
                for (int j = 0; j < TOPK; ++j) {
                    float mx = fmaxf(t[j], v);
                    v = fminf(t[j], v);
                    t[j] = mx;
                }
            }
        }

#pragma unroll
        for (int stage = 0; stage < 2; ++stage) {
            const int xm = 16 << stage;
            float bl[TOPK], c[TOPK];
#pragma unroll
            for (int j = 0; j < TOPK; ++j) bl[j] = __shfl_xor(t[j], xm, 64);
#pragma unroll
            for (int j = 0; j < TOPK; ++j) c[j] = fmaxf(t[j], bl[TOPK - 1 - j]);
#pragma unroll
            for (int s = 8; s >= 1; s >>= 1) {
#pragma unroll
                for (int i = 0; i < TOPK; ++i) {
                    if ((i & s) == 0) {
                        float mx = fmaxf(c[i], c[i + s]);
                        c[i + s] = fminf(c[i], c[i + s]);
                        c[i] = mx;
                    }
                }
            }
#pragma unroll
            for (int j = 0; j < TOPK; ++j) t[j] = c[j];
        }

        if (q == 0 && nrow < SEQ) {
            float e[TOPK], sum = 0.f;
#pragma unroll
            for (int j = 0; j < TOPK; ++j) { e[j] = __expf((t[j] - t[0]) * SCALE_F); sum += e[j]; }
            float inv = 1.0f / sum;
            unsigned int pk[8];
#pragma unroll
            for (int jj = 0; jj < 8; ++jj)
                pk[jj] = (unsigned int)f2b(e[2 * jj] * inv) |
                         ((unsigned int)f2b(e[2 * jj + 1] * inv) << 16);
            unsigned short* dst = aout + ((size_t)(b * SEQ + nrow)) * (NHEAD * TOPK) + h * TOPK;
            ((uint4*)dst)[0] = make_uint4(pk[0], pk[1], pk[2], pk[3]);
            ((uint4*)dst)[1] = make_uint4(pk[4], pk[5], pk[6], pk[7]);
        }
    }
}

// ---------------- Launch ----------------
extern "C" void kernel_launch(void* const* d_in, const int* in_sizes, int n_in,
                              void* d_out, int out_size, void* d_ws, size_t ws_size,
                              hipStream_t stream)
{
    const float* x    = (const float*)d_in[0];
    const float* g1   = (const float*)d_in[1];
    const float* bb1  = (const float*)d_in[2];
    const float* qkw  = (const float*)d_in[3];
    const float* pw   = (const float*)d_in[4];
    const float* pb   = (const float*)d_in[5];
    const float* g2   = (const float*)d_in[6];
    const float* bb2  = (const float*)d_in[7];
    const float* f1w  = (const float*)d_in[8];
    const float* f1b  = (const float*)d_in[9];
    const float* f2w  = (const float*)d_in[10];
    const float* f2bp = (const float*)d_in[11];
    float* out = (float*)d_out;

    // layout: hbuf | weights(wqk,wp,wf1,wf2) | av | qk/gg
    char* ws = (char*)d_ws;
    const size_t SZ_H   = (size_t)MROWS * CH * 2;              // 19,267,584
    const size_t N_WQK  = (size_t)2 * CH * CH;                 // 1,179,648 elems
    const size_t N_WP   = (size_t)CH * (NHEAD * TOPK);         //   147,456
    const size_t N_WF   = (size_t)HID * CH;                    // 2,359,296
    const size_t SZ_W   = (N_WQK + N_WP + 2 * N_WF) * 2;       // 12,091,392
    const size_t SZ_A   = (size_t)MROWS * (NHEAD * TOPK) * 2;  //  4,816,896
    const size_t SZ_GGF = (size_t)MROWS * HID * 2;             // 77,070,336

    unsigned short* hbuf = (unsigned short*)(ws);
    unsigned short* wqk  = (unsigned short*)(ws + SZ_H);
    unsigned short* wp   = wqk + N_WQK;
    unsigned short* wf1  = wp  + N_WP;
    unsigned short* wf2  = wf1 + N_WF;
    unsigned short* av   = (unsigned short*)(ws + SZ_H + SZ_W);
    unsigned short* qk   = (unsigned short*)(ws + SZ_H + SZ_W + SZ_A);
    unsigned short* gg   = qk;   // overlays qk (dead by MLP time)
    float* x1 = out;             // residual stream after attention lives in d_out

    const bool fullMLP = ws_size >= SZ_H + SZ_W + SZ_A + SZ_GGF;   // 113.25 MB

    // 0) all weights f32 -> bf16, one dispatch
    {
        int total4 = (int)((N_WQK + N_WP + 2 * N_WF) / 4);
        f2b4_k<<<(total4 + 255) / 256, 256, 0, stream>>>(
            qkw, wqk, (int)N_WQK, pw, wp, (int)N_WP,
            f1w, wf1, (int)N_WF, f2w, wf2, (int)N_WF);
    }

    // 1) LN1: x -> h (bf16)
    ln_k<<<MROWS, 256, 0, stream>>>(x, g1, bb1, hbuf);
    // 2) qk = h @ qk_w^T   [12544 x 1536], K=768   (128x128: grid 12x98)
    gemm_bt<128, 128, false, false, false, false><<<dim3(12, 98), 256, 0, stream>>>(
        hbuf, wqk, nullptr, nullptr, qk, MROWS, 2*CH, CH);
    // 3) attention -> top16 softmax weights [12544 x 192] bf16
    attn_topk<<<BATCH * NHEAD, 256, 0, stream>>>(qk, av);
    // 4) x1 = x + a @ attn_proj_w^T + b   [12544 x 768], K=192   (64x128: grid 6x196)
    gemm_bt<64, 128, true, true, false, true><<<dim3(6, 196), 256, 0, stream>>>(
        av, wp, pb, x, x1, MROWS, CH, NHEAD*TOPK);
    // 5) LN2: x1 -> h2 (reuse hbuf)
    ln_k<<<MROWS, 256, 0, stream>>>(x1, g2, bb2, hbuf);

    // 6/7) MLP: full-M if workspace allows (gg = 77 MB), else two M-halves
    if (fullMLP) {
        gemm_bt<128, 128, true, false, true, false><<<dim3(24, 98), 256, 0, stream>>>(
            hbuf, wf1, f1b, nullptr, gg, MROWS, HID, CH);
        // fc2: 64x256 tile (grid 3x196) — gg refetch 6x -> 3x, XCD-local stripes
        gemm_bt<64, 256, true, true, false, true><<<dim3(3, 196), 256, 0, stream>>>(
            gg, wf2, f2bp, x1, out, MROWS, CH, HID);
    } else {
        for (int half = 0; half < 2; ++half) {
            const size_t ro = (size_t)half * MHALF;
            gemm_bt<128, 128, true, false, true, false><<<dim3(24, 49), 256, 0, stream>>>(
                hbuf + ro * CH, wf1, f1b, nullptr, gg, MHALF, HID, CH);
            gemm_bt<64, 256, true, true, false, true><<<dim3(3, 98), 256, 0, stream>>>(
                gg, wf2, f2bp, x1 + ro * CH, out + ro * CH, MHALF, CH, HID);
        }
    }
}

// Round 10
// 433.482 us; speedup vs baseline: 2.8844x; 1.0134x over previous
//
#include <hip/hip_runtime.h>

// Block_58394375356873: HomoAttention transformer block, MI355X gfx950.
// I/O dtype: float32 (per reference). Internal GEMM compute: bf16 MFMA.
// M = B*N = 64*196 = 12544.

#define BATCH 64
#define SEQ   196
#define CH    768
#define NHEAD 12
#define HDIM  64
#define TOPK  16
#define HID   3072
#define MROWS 12544
#define MHALF 6272
#define SCALE_F 0.125f  // 64^-0.5
#define NEGBIG -3e38f

typedef __bf16 bf16x8 __attribute__((ext_vector_type(8)));
typedef float  f32x4  __attribute__((ext_vector_type(4)));

__device__ __forceinline__ unsigned short f2b(float f) {
    union { float f; unsigned int i; } c; c.f = f;
    unsigned int u = c.i;
    return (unsigned short)((u + 0x7fffu + ((u >> 16) & 1u)) >> 16); // RNE
}
__device__ __forceinline__ float b2f(unsigned short u) {
    union { unsigned int i; float f; } c; c.i = ((unsigned int)u) << 16; return c.f;
}

// tanh-form GELU, |err vs exact erf-GELU| < 4e-4, ~10 VALU ops (vs ~40 for libm erff).
// Overflow-safe: e=inf -> th=1 -> v; e=0 -> th=-1 -> 0.
__device__ __forceinline__ float gelu_f(float v) {
    float u = v * (0.7978845608f + 0.0356774081f * v * v);
    float e = __expf(2.0f * u);
    float th = 1.0f - 2.0f / (e + 1.0f);
    return 0.5f * v * (1.0f + th);
}

// async global->LDS, 16B per lane. LDS base must be wave-uniform; HW adds lane*16.
__device__ __forceinline__ void async16(const unsigned short* g, unsigned short* l) {
    __builtin_amdgcn_global_load_lds(
        (const __attribute__((address_space(1))) unsigned int*)(g),
        (__attribute__((address_space(3))) unsigned int*)(l), 16, 0, 0);
}

// ---------------- all-weights f32 -> bf16, one dispatch ----------------
__global__ __launch_bounds__(256) void f2b4_k(const float* __restrict__ s0, unsigned short* __restrict__ d0, int n0,
                                              const float* __restrict__ s1, unsigned short* __restrict__ d1, int n1,
                                              const float* __restrict__ s2, unsigned short* __restrict__ d2, int n2,
                                              const float* __restrict__ s3, unsigned short* __restrict__ d3, int n3)
{
    int idx = (blockIdx.x * 256 + threadIdx.x) * 4;
    const float* s; unsigned short* d; int n;
    if (idx < n0) { s = s0; d = d0; n = n0; }
    else {
        idx -= n0;
        if (idx < n1) { s = s1; d = d1; n = n1; }
        else {
            idx -= n1;
            if (idx < n2) { s = s2; d = d2; n = n2; }
            else { idx -= n2; s = s3; d = d3; n = n3; }
        }
    }
    if (idx < n) {
        float4 v = *(const float4*)(s + idx);
        ushort4 o;
        o.x = f2b(v.x); o.y = f2b(v.y); o.z = f2b(v.z); o.w = f2b(v.w);
        *(ushort4*)(d + idx) = o;
    }
}

// ---------------- LayerNorm: f32|bf16 in -> bf16 out, one block per row ----------------
template<bool INF32>
__global__ __launch_bounds__(256) void ln_k(const void* __restrict__ xin,
                                            const float* __restrict__ gw,
                                            const float* __restrict__ bw,
                                            unsigned short* __restrict__ out)
{
    const int row = blockIdx.x;
    const int tid = threadIdx.x;
    float v0, v1, v2;
    if constexpr (INF32) {
        const float* xr = (const float*)xin + (size_t)row * CH;
        v0 = xr[tid]; v1 = xr[tid + 256]; v2 = xr[tid + 512];
    } else {
        const unsigned short* xr = (const unsigned short*)xin + (size_t)row * CH;
        v0 = b2f(xr[tid]); v1 = b2f(xr[tid + 256]); v2 = b2f(xr[tid + 512]);
    }
    float s  = v0 + v1 + v2;
    float sq = v0*v0 + v1*v1 + v2*v2;
#pragma unroll
    for (int off = 32; off > 0; off >>= 1) {
        s  += __shfl_down(s, off, 64);
        sq += __shfl_down(sq, off, 64);
    }
    __shared__ __align__(16) float red[8];
    if ((tid & 63) == 0) { red[(tid >> 6) * 2] = s; red[(tid >> 6) * 2 + 1] = sq; }
    __syncthreads();
    s  = red[0] + red[2] + red[4] + red[6];
    sq = red[1] + red[3] + red[5] + red[7];
    float mu  = s * (1.0f / CH);
    float var = sq * (1.0f / CH) - mu * mu;
    float rs  = rsqrtf(var + 1e-5f);
    unsigned short* orow = out + (size_t)row * CH;
    orow[tid]       = f2b((v0 - mu) * rs * gw[tid]       + bw[tid]);
    orow[tid + 256] = f2b((v1 - mu) * rs * gw[tid + 256] + bw[tid + 256]);
    orow[tid + 512] = f2b((v2 - mu) * rs * gw[tid + 512] + bw[tid + 512]);
}

// ---------------- NT GEMM: C[M,N] = A[M,K] @ W[N,K]^T (+bias)(+gelu)(+resid) ----
// TM x TN tile, BK=32, 256 threads = 4 waves. TM=128: waves 2x2. TM=64: 1x4.
// Double-buffered width-16 global_load_lds, one barrier per K-iter; staging
// pointers pre-advanced (no per-iter address mul).
// RES: 0=none, 1=f32 resid, 2=bf16 resid. OUTF: f32 (true) or bf16 out.
// XCD-locality swizzle: gridN blocks sharing an A M-stripe get ids congruent
// mod 8 -> same XCD -> stripe L2-served after first fetch.
template<int TM, int TN, bool BIAS, int RES, bool GELU, bool OUTF>
__global__ __launch_bounds__(256, 4)
void gemm_bt(const unsigned short* __restrict__ A,
             const unsigned short* __restrict__ Bw,
             const float* __restrict__ bias,
             const void* __restrict__ resid,
             void* __restrict__ Cout,
             int M, int N, int K)
{
    constexpr int WROWS = (TM == 128) ? 2 : 1;
    constexpr int WCOLS = 4 / WROWS;
    constexpr int JF = TN / (16 * WCOLS);           // frag cols per wave
    __shared__ __align__(16) unsigned short As[2][TM * 32];
    __shared__ __align__(16) unsigned short Bs[2][TN * 32];
    const int tid  = threadIdx.x;
    const int w    = tid >> 6;
    const int lane = tid & 63;

    // XCD-locality block remap (supergroups of 8 M-stripes x gridN)
    const int gridN = gridDim.x, gridM = gridDim.y;
    const int lid = blockIdx.y * gridN + blockIdx.x;
    const int SG = 8 * gridN;
    const int sg = lid / SG, r = lid % SG;
    const int remM = gridM - sg * 8;
    int mloc, nloc;
    if (remM >= 8) { mloc = sg * 8 + (r & 7); nloc = r >> 3; }
    else           { mloc = sg * 8 + r % remM; nloc = r / remM; }
    const int tileM = mloc * TM;
    const int tileN = nloc * TN;

    const int wm = (w / WCOLS) * 64;                // TM=64 -> 0
    const int wn = (w % WCOLS) * (JF * 16);
    const int q   = lane >> 4;
    const int l16 = lane & 15;
    const int csw = (q ^ (l16 & 3)) * 8;            // swizzled chunk offset for frag reads

    f32x4 acc[4][JF];
#pragma unroll
    for (int i = 0; i < 4; ++i)
#pragma unroll
        for (int j = 0; j < JF; ++j) acc[i][j] = (f32x4){0.f, 0.f, 0.f, 0.f};

    // staging: chunk idx -> row = idx>>2, slot = idx&3, global chunk = slot^(row&3)
    const int r0 = tid >> 2;
    const int g0 = ((tid & 3) ^ (r0 & 3)) * 8;      // (row+64k)&3 == row&3: same for all c

    const unsigned short* pB[TN / 64];
    const unsigned short* pA[TM / 64];
#pragma unroll
    for (int c = 0; c < TN / 64; ++c) pB[c] = Bw + (size_t)(tileN + r0 + c * 64) * K + g0;
#pragma unroll
    for (int c = 0; c < TM / 64; ++c) pA[c] = A + (size_t)(tileM + r0 + c * 64) * K + g0;

    auto stage = [&](int buf) {
#pragma unroll
        for (int c = 0; c < TN / 64; ++c) {
            async16(pB[c], &Bs[buf][(size_t)(c * 256 + w * 64) * 8]);
            pB[c] += 32;
        }
#pragma unroll
        for (int c = 0; c < TM / 64; ++c) {
            async16(pA[c], &As[buf][(size_t)(c * 256 + w * 64) * 8]);
            pA[c] += 32;
        }
    };

    const int kIters = K >> 5;
    stage(0);
    int cur = 0;
    for (int kt = 0; kt < kIters; ++kt) {
        __syncthreads();   // drains vmcnt: buf[cur] landed; prior LDS reads done
        if (kt + 1 < kIters) stage(cur ^ 1);   // flies through compute phase
        bf16x8 af[4], bfr[JF];
#pragma unroll
        for (int i = 0; i < 4; ++i)
            af[i] = *(const bf16x8*)&As[cur][(wm + i * 16 + l16) * 32 + csw];
#pragma unroll
        for (int j = 0; j < JF; ++j)
            bfr[j] = *(const bf16x8*)&Bs[cur][(wn + j * 16 + l16) * 32 + csw];
#pragma unroll
        for (int i = 0; i < 4; ++i)
#pragma unroll
            for (int j = 0; j < JF; ++j)
                acc[i][j] = __builtin_amdgcn_mfma_f32_16x16x32_bf16(af[i], bfr[j], acc[i][j], 0, 0, 0);
        cur ^= 1;
    }

#pragma unroll
    for (int i = 0; i < 4; ++i) {
#pragma unroll
        for (int r2 = 0; r2 < 4; ++r2) {
            int row = tileM + wm + i * 16 + q * 4 + r2;  // C/D: col=lane&15, row=quad*4+reg
#pragma unroll
            for (int j = 0; j < JF; ++j) {
                int col = tileN + wn + j * 16 + l16;
                float v = acc[i][j][r2];
                if (BIAS) v += bias[col];
                if (GELU) v = gelu_f(v);
                if (RES == 1) v += ((const float*)resid)[(size_t)row * N + col];
                if (RES == 2) v += b2f(((const unsigned short*)resid)[(size_t)row * N + col]);
                if (OUTF) ((float*)Cout)[(size_t)row * N + col] = v;
                else      ((unsigned short*)Cout)[(size_t)row * N + col] = f2b(v);
            }
        }
    }
}

// ---------------- Attention: MFMA scores + in-register top-16 + softmax ----------------
// One block per (b,h). S^T = K @ Q^T via mfma_f32_16x16x32_bf16 (A=K: D-row=m,
// B=Q: D-col=n). Lane l16 owns column n; quad q sees m = tm*16 + q*4 + r.
// Per-lane sorted top-16, then 2 cross-quad bitonic merges (shfl_xor 16, 32).
// LDS: Q,K [208][64] bf16, 16B-chunk XOR swizzle (chunk ^ (row&7)): conflict-free.
__global__ __launch_bounds__(256) void attn_topk(const unsigned short* __restrict__ qk,
                                                 unsigned short* __restrict__ aout)
{
    const int bh = blockIdx.x;
    const int b = bh / NHEAD, h = bh % NHEAD;
    __shared__ __align__(16) unsigned short Qs[208 * 64];
    __shared__ __align__(16) unsigned short Ks[208 * 64];
    const int tid = threadIdx.x;

    for (int i = tid; i < 208 * 8; i += 256) {
        int row = i >> 3, c = i & 7;
        uint4 vq = make_uint4(0, 0, 0, 0), vk = vq;
        if (row < SEQ) {
            const uint4* gp = (const uint4*)(qk + ((size_t)(b * SEQ + row) * 1536 + h * 64));
            vq = gp[c];        // q half
            vk = gp[c + 96];   // k half: +768 shorts = +96 uint4
        }
        int slot = c ^ (row & 7);
        *(uint4*)&Qs[row * 64 + slot * 8] = vq;
        *(uint4*)&Ks[row * 64 + slot * 8] = vk;
    }
    __syncthreads();

    const int w = tid >> 6, lane = tid & 63;
    const int q = lane >> 4, l16 = lane & 15;

    for (int tn = w; tn < 13; tn += 4) {
        const int nrow = tn * 16 + l16;
        const int nsw = nrow & 7;
        bf16x8 bq0 = *(const bf16x8*)&Qs[nrow * 64 + ((0 * 4 + q) ^ nsw) * 8];
        bf16x8 bq1 = *(const bf16x8*)&Qs[nrow * 64 + ((1 * 4 + q) ^ nsw) * 8];

        float t[TOPK];
#pragma unroll
        for (int j = 0; j < TOPK; ++j) t[j] = NEGBIG;

        for (int tm = 0; tm < 12; ++tm) {
            const int mrow = tm * 16 + l16;
            const int msw = mrow & 7;
            bf16x8 ak0 = *(const bf16x8*)&Ks[mrow * 64 + ((0 * 4 + q) ^ msw) * 8];
            bf16x8 ak1 = *(const bf16x8*)&Ks[mrow * 64 + ((1 * 4 + q) ^ msw) * 8];
            f32x4 acc = (f32x4){0.f, 0.f, 0.f, 0.f};
            acc = __builtin_amdgcn_mfma_f32_16x16x32_bf16(ak0, bq0, acc, 0, 0, 0);
            acc = __builtin_amdgcn_mfma_f32_16x16x32_bf16(ak1, bq1, acc, 0, 0, 0);
#pragma unroll
            for (int r = 0; r < 4; ++r) {
                float v = acc[r];
#pragma unroll
                for (int j = 0; j < TOPK; ++j) {
                    float mx = fmaxf(t[j], v);
                    v = fminf(t[j], v);
                    t[j] = mx;
                }
            }
        }
        {   // m-tile 12: m = 192 + q*4 + r valid only for q==0
            const int mrow = 12 * 16 + l16;
            const int msw = mrow & 7;
            bf16x8 ak0 = *(const bf16x8*)&Ks[mrow * 64 + ((0 * 4 + q) ^ msw) * 8];
            bf16x8 ak1 = *(const bf16x8*)&Ks[mrow * 64 + ((1 * 4 + q) ^ msw) * 8];
            f32x4 acc = (f32x4){0.f, 0.f, 0.f, 0.f};
            acc = __builtin_amdgcn_mfma_f32_16x16x32_bf16(ak0, bq0, acc, 0, 0, 0);
            acc = __builtin_amdgcn_mfma_f32_16x16x32_bf16(ak1, bq1, acc, 0, 0, 0);
#pragma unroll
            for (int r = 0; r < 4; ++r) {
                float v = (q == 0) ? acc[r] : NEGBIG;
#pragma unroll
                for (int j = 0; j < TOPK; ++j) {
                    float mx = fmaxf(t[j], v);
                    v = fminf(t[j], v);
                    t[j] = mx;
                }
            }
        }

#pragma unroll
        for (int stage = 0; stage < 2; ++stage) {
            const int xm = 16 << stage;
            float bl[TOPK], c[TOPK];
#pragma unroll
            for (int j = 0; j < TOPK; ++j) bl[j] = __shfl_xor(t[j], xm, 64);
#pragma unroll
            for (int j = 0; j < TOPK; ++j) c[j] = fmaxf(t[j], bl[TOPK - 1 - j]);
#pragma unroll
            for (int s = 8; s >= 1; s >>= 1) {
#pragma unroll
                for (int i = 0; i < TOPK; ++i) {
                    if ((i & s) == 0) {
                        float mx = fmaxf(c[i], c[i + s]);
                        c[i + s] = fminf(c[i], c[i + s]);
                        c[i] = mx;
                    }
                }
            }
#pragma unroll
            for (int j = 0; j < TOPK; ++j) t[j] = c[j];
        }

        if (q == 0 && nrow < SEQ) {
            float e[TOPK], sum = 0.f;
#pragma unroll
            for (int j = 0; j < TOPK; ++j) { e[j] = __expf((t[j] - t[0]) * SCALE_F); sum += e[j]; }
            float inv = 1.0f / sum;
            unsigned int pk[8];
#pragma unroll
            for (int jj = 0; jj < 8; ++jj)
                pk[jj] = (unsigned int)f2b(e[2 * jj] * inv) |
                         ((unsigned int)f2b(e[2 * jj + 1] * inv) << 16);
            unsigned short* dst = aout + ((size_t)(b * SEQ + nrow)) * (NHEAD * TOPK) + h * TOPK;
            ((uint4*)dst)[0] = make_uint4(pk[0], pk[1], pk[2], pk[3]);
            ((uint4*)dst)[1] = make_uint4(pk[4], pk[5], pk[6], pk[7]);
        }
    }
}

// ---------------- Launch ----------------
extern "C" void kernel_launch(void* const* d_in, const int* in_sizes, int n_in,
                              void* d_out, int out_size, void* d_ws, size_t ws_size,
                              hipStream_t stream)
{
    const float* x    = (const float*)d_in[0];
    const float* g1   = (const float*)d_in[1];
    const float* bb1  = (const float*)d_in[2];
    const float* qkw  = (const float*)d_in[3];
    const float* pw   = (const float*)d_in[4];
    const float* pb   = (const float*)d_in[5];
    const float* g2   = (const float*)d_in[6];
    const float* bb2  = (const float*)d_in[7];
    const float* f1w  = (const float*)d_in[8];
    const float* f1b  = (const float*)d_in[9];
    const float* f2w  = (const float*)d_in[10];
    const float* f2bp = (const float*)d_in[11];
    float* out = (float*)d_out;

    // layout: hbuf | weights(wqk,wp,wf1,wf2) | av | qk/gg | x1b
    char* ws = (char*)d_ws;
    const size_t SZ_H   = (size_t)MROWS * CH * 2;              // 19,267,584
    const size_t N_WQK  = (size_t)2 * CH * CH;
    const size_t N_WP   = (size_t)CH * (NHEAD * TOPK);
    const size_t N_WF   = (size_t)HID * CH;
    const size_t SZ_W   = (N_WQK + N_WP + 2 * N_WF) * 2;       // 12,091,392
    const size_t SZ_A   = (size_t)MROWS * (NHEAD * TOPK) * 2;  //  4,816,896
    const size_t SZ_QK  = (size_t)MROWS * 2 * CH * 2;          // 38,535,168
    const size_t SZ_GGF = (size_t)MROWS * HID * 2;             // 77,070,336

    unsigned short* hbuf = (unsigned short*)(ws);
    unsigned short* wqk  = (unsigned short*)(ws + SZ_H);
    unsigned short* wp   = wqk + N_WQK;
    unsigned short* wf1  = wp  + N_WP;
    unsigned short* wf2  = wf1 + N_WF;
    unsigned short* av   = (unsigned short*)(ws + SZ_H + SZ_W);
    unsigned short* qk   = (unsigned short*)(ws + SZ_H + SZ_W + SZ_A);
    unsigned short* gg   = qk;   // overlays qk (dead by MLP time)

    const size_t base = SZ_H + SZ_W + SZ_A;
    const bool fullMLP = ws_size >= base + SZ_GGF + SZ_H;      // 132.5 MB: full-M + bf16 x1
    const bool bx1     = fullMLP || ws_size >= base + SZ_QK + SZ_H;  // 94 MB: halves + bf16 x1
    unsigned short* x1b = (unsigned short*)(ws + base + (fullMLP ? SZ_GGF : SZ_QK));
    float* x1 = out;   // f32 fallback residual lives in d_out

    // 0) all weights f32 -> bf16, one dispatch
    {
        int total4 = (int)((N_WQK + N_WP + 2 * N_WF) / 4);
        f2b4_k<<<(total4 + 255) / 256, 256, 0, stream>>>(
            qkw, wqk, (int)N_WQK, pw, wp, (int)N_WP,
            f1w, wf1, (int)N_WF, f2w, wf2, (int)N_WF);
    }

    // 1) LN1: x(f32) -> h (bf16)
    ln_k<true><<<MROWS, 256, 0, stream>>>(x, g1, bb1, hbuf);
    // 2) qk = h @ qk_w^T   [12544 x 1536], K=768   (128x128: grid 12x98)
    gemm_bt<128, 128, false, 0, false, false><<<dim3(12, 98), 256, 0, stream>>>(
        hbuf, wqk, nullptr, nullptr, qk, MROWS, 2*CH, CH);
    // 3) attention -> top16 softmax weights [12544 x 192] bf16
    attn_topk<<<BATCH * NHEAD, 256, 0, stream>>>(qk, av);

    if (bx1) {
        // 4) x1b = bf16(x + a @ attn_proj_w^T + b)   (64x128: grid 6x196)
        gemm_bt<64, 128, true, 1, false, false><<<dim3(6, 196), 256, 0, stream>>>(
            av, wp, pb, x, x1b, MROWS, CH, NHEAD*TOPK);
        // 5) LN2: x1b (bf16) -> h2
        ln_k<false><<<MROWS, 256, 0, stream>>>(x1b, g2, bb2, hbuf);
        if (fullMLP) {
            gemm_bt<128, 128, true, 0, true, false><<<dim3(24, 98), 256, 0, stream>>>(
                hbuf, wf1, f1b, nullptr, gg, MROWS, HID, CH);
            gemm_bt<64, 256, true, 2, false, true><<<dim3(3, 196), 256, 0, stream>>>(
                gg, wf2, f2bp, x1b, out, MROWS, CH, HID);
        } else {
            for (int half = 0; half < 2; ++half) {
                const size_t ro = (size_t)half * MHALF;
                gemm_bt<128, 128, true, 0, true, false><<<dim3(24, 49), 256, 0, stream>>>(
                    hbuf + ro * CH, wf1, f1b, nullptr, gg, MHALF, HID, CH);
                gemm_bt<64, 256, true, 2, false, true><<<dim3(3, 98), 256, 0, stream>>>(
                    gg, wf2, f2bp, x1b + ro * CH, out + ro * CH, MHALF, CH, HID);
            }
        }
    } else {
        // conservative fallback: f32 x1 in d_out, halved MLP (74.7 MB ws)
        gemm_bt<64, 128, true, 1, false, true><<<dim3(6, 196), 256, 0, stream>>>(
            av, wp, pb, x, x1, MROWS, CH, NHEAD*TOPK);
        ln_k<true><<<MROWS, 256, 0, stream>>>(x1, g2, bb2, hbuf);
        for (int half = 0; half < 2; ++half) {
            const size_t ro = (size_t)half * MHALF;
            gemm_bt<128, 128, true, 0, true, false><<<dim3(24, 49), 256, 0, stream>>>(
                hbuf + ro * CH, wf1, f1b, nullptr, gg, MHALF, HID, CH);
            gemm_bt<64, 256, true, 1, false, true><<<dim3(3, 98), 256, 0, stream>>>(
                gg, wf2, f2bp, x1 + ro * CH, out + ro * CH, MHALF, CH, HID);
        }
    }
}